// Round 17
// baseline (1430.316 us; speedup 1.0000x reference)
//
#include <hip/hip_runtime.h>
#include <hip/hip_bf16.h>

#define NN 50000
#define NE 200000
#define HEADS 4
#define EPSV 1e-5f
#define NEGS 0.01f

using f32x4 = __attribute__((ext_vector_type(4))) float;
using s16x8 = __attribute__((ext_vector_type(8))) short;
using bf16x8 = __attribute__((ext_vector_type(8))) __bf16;

__device__ __forceinline__ short f2bf(float f) {
    union { float f; unsigned u; } v; v.f = f;
    unsigned r = v.u + 0x7FFFu + ((v.u >> 16) & 1u);
    return (short)(r >> 16);
}
__device__ __forceinline__ float bf2f(short s) {
    union { unsigned u; float f; } v; v.u = ((unsigned)(unsigned short)s) << 16;
    return v.f;
}
__device__ __forceinline__ f32x4 mfma16(s16x8 a, s16x8 b, f32x4 c) {
    return __builtin_amdgcn_mfma_f32_16x16x32_bf16(
        __builtin_bit_cast(bf16x8, a), __builtin_bit_cast(bf16x8, b), c, 0, 0, 0);
}
__device__ __forceinline__ void gld16(const void* g, void* l) {
    __builtin_amdgcn_global_load_lds(
        (const __attribute__((address_space(1))) void*)g,
        (__attribute__((address_space(3))) void*)l, 16, 0, 0);
}
// DMA one 16KB chunk (8192 shorts) image -> LDS, 256 threads, 4 ops each
__device__ __forceinline__ void dma16(const short* src, char* dst, int w, int lane) {
    #pragma unroll
    for (int op = 0; op < 4; ++op)
        gld16(src + op * 2048 + w * 512 + lane * 8, dst + op * 4096 + w * 1024);
}

// ---------------- weight prep (unchanged, verified) ----------------
__global__ void prep_weights(const float* __restrict__ Kv2v, const float* __restrict__ Vv2v,
                             const float* __restrict__ inpW,
                             const float* __restrict__ Ke2v, const float* __restrict__ Ve2v,
                             const float* __restrict__ luW, const float* __restrict__ msgW,
                             const float* __restrict__ catW,
                             short* __restrict__ nodeW_t, short* __restrict__ imgW)
{
    int i = blockIdx.x * 256 + threadIdx.x;
    if (i < 147456) {                       // nodeW_t [1152][128]
        int j = i >> 7, k = i & 127;
        float v;
        if (j < 512)       v = Kv2v[(j >> 7) * 16384 + k * 128 + (j & 127)];
        else if (j < 1024) v = Vv2v[((j - 512) >> 7) * 16384 + k * 128 + (j & 127)];
        else               v = inpW[k * 128 + (j - 1024)];
        nodeW_t[i] = f2bf(v);
        return;
    }
    i -= 147456;
    if (i >= 589824) return;
    int h = i / 147456;
    int r = i % 147456;
    short* img = imgW + h * 147456;
    if (r < 16384) {                        // KW (K=128)
        int colc = r >> 7, k = r & 127;
        img[(colc * 128 + k) ^ ((colc & 7) << 3)] = f2bf(Ke2v[h * 16384 + k * 128 + colc]);
    } else if (r < 32768) {                 // VW (K=128)
        int e = r - 16384; int colc = e >> 7, k = e & 127;
        img[16384 + ((colc * 128 + k) ^ ((colc & 7) << 3))] = f2bf(Ve2v[h * 16384 + k * 128 + colc]);
    } else if (r < 98304) {                 // LU (K=256)
        int e = r - 32768; int c = e >> 14, ec = e & 16383;
        int colc = ec >> 8, k = ec & 255; int col = c * 64 + colc;
        img[32768 + c * 16384 + ((colc * 256 + k) ^ ((colc & 7) << 3))] =
            f2bf(luW[h * 65536 + k * 256 + col]);
    } else if (r < 131072) {                // MSG (K=256)
        int e = r - 98304; int c = e >> 14, ec = e & 16383;
        int colc = ec >> 8, k = ec & 255; int col = c * 64 + colc;
        img[98304 + c * 16384 + ((colc * 256 + k) ^ ((colc & 7) << 3))] =
            f2bf(msgW[h * 32768 + k * 128 + col]);
    } else {                                // CAT (K=128)
        int e = r - 131072; int colc = e >> 7, k = e & 127;
        img[131072 + ((colc * 128 + k) ^ ((colc & 7) << 3))] =
            f2bf(catW[(h * 128 + k) * 128 + colc]);
    }
}

// ---------------- node projections (unchanged, verified) ----------------
__global__ __launch_bounds__(256, 2)
void node_proj(const float* __restrict__ x, const short* __restrict__ nodeW_t,
               short* __restrict__ Kv_all, short* __restrict__ Vv_all,
               float* __restrict__ resid)
{
    __shared__ alignas(16) short xt[64 * 128];
    const int tid = threadIdx.x;
    const int row0 = blockIdx.x * 64;
    #pragma unroll
    for (int it = 0; it < 8; ++it) {
        int idx4 = it * 256 + tid;
        int r = idx4 >> 5;
        int c = (idx4 & 31) * 4;
        float4 v = {0.f, 0.f, 0.f, 0.f};
        if (row0 + r < NN) v = *(const float4*)(x + (size_t)(row0 + r) * 128 + c);
        short4 sw; sw.x = f2bf(v.x); sw.y = f2bf(v.y); sw.z = f2bf(v.z); sw.w = f2bf(v.w);
        int byte = (r * 256 + c * 2) ^ ((r & 7) << 4);
        *(short4*)((char*)xt + byte) = sw;
    }
    __syncthreads();
    const int lane = tid & 63, w = tid >> 6;
    const int l15 = lane & 15, lg = lane >> 4;
    const int rloc = w * 16 + l15;
    s16x8 a[4];
    #pragma unroll
    for (int ks = 0; ks < 4; ++ks) {
        int byte = (rloc * 256 + (ks * 32 + lg * 8) * 2) ^ ((rloc & 7) << 4);
        a[ks] = *(const s16x8*)((const char*)xt + byte);
    }
    const int rowC = row0 + w * 16 + lg * 4;
    for (int nc = 0; nc < 18; ++nc) {
        f32x4 acc[4];
        s16x8 b[16];
        #pragma unroll
        for (int q = 0; q < 4; ++q) {
            acc[q] = (f32x4){0.f, 0.f, 0.f, 0.f};
            int j = (nc * 4 + q) * 16 + l15;
            #pragma unroll
            for (int ks = 0; ks < 4; ++ks)
                b[q * 4 + ks] = *(const s16x8*)(nodeW_t + j * 128 + ks * 32 + lg * 8);
        }
        #pragma unroll
        for (int q = 0; q < 4; ++q)
            #pragma unroll
            for (int ks = 0; ks < 4; ++ks)
                acc[q] = mfma16(a[ks], b[q * 4 + ks], acc[q]);
        #pragma unroll
        for (int q = 0; q < 4; ++q) {
            int j = (nc * 4 + q) * 16 + l15;
            #pragma unroll
            for (int r = 0; r < 4; ++r) {
                int row = rowC + r;
                if (row >= NN) continue;
                if (j < 512)       Kv_all[(size_t)row * 512 + j] = f2bf(acc[q][r]);
                else if (j < 1024) Vv_all[(size_t)row * 512 + (j - 512)] = f2bf(acc[q][r]);
                else               resid[(size_t)row * 128 + (j - 1024)] = acc[q][r];
            }
        }
    }
}

// ---------------- fused edge pipeline: R16 base + PADDED scratch (bank-conflict fix) ----------------
// Dynamic LDS 137216:
//   wbuf[4] @ 0..65535 (4 x 16KB)
//   per-wave scratch @65536 + w*13312:
//     q  @0     [16] rows x 272B  (was 256 -> all rows bank-aliased; 272=17 dwords
//     k1 @4352  [16] rows x 272B   spreads row r to bank 4r%32 -> scalar 2B ops
//     VE @8704  [16] rows x 272B   go from 4-8 way conflict to ~conflict-free)
//     m1g overlays q+k1 @0: [16] rows x 528B (8448 <= 8704)
//     m2 overlays VE @8704
//   bias tables @118784 (floats)
// Address formula everywhere: row*stride + (colbyte ^ ((row&7)<<4)); colbyte
// stays < stride so the XOR involution is self-contained per row.
#define B128h(buf, ct, ks) \
    (*(const s16x8*)((const short*)(buf) + (((((ct) * 16 + l15) * 128) + (ks) * 32 + lg * 8) ^ ((l15 & 7) << 3))))
#define B256h(buf, tt, ks) \
    (*(const s16x8*)((const short*)(buf) + (((((tt) * 16 + l15) * 256) + (ks) * 32 + lg * 8) ^ ((l15 & 7) << 3))))
#define WAITV(N) asm volatile("s_waitcnt vmcnt(" #N ")" ::: "memory")
#define SBAR() do { __builtin_amdgcn_s_barrier(); __builtin_amdgcn_sched_barrier(0); } while (0)
#define PRIO1() __builtin_amdgcn_s_setprio(1)
#define PRIO0() __builtin_amdgcn_s_setprio(0)
#define STEP_SYNC(s) do { \
    if (h < 3 || (s) < 16) { WAITV(8); } \
    else if ((s) == 16)    { WAITV(4); } \
    else                   { WAITV(0); } \
    SBAR(); \
    if ((s) <= 14)      dma16(hb + ((s) + 3) * 8192, lds + ((ph + (s) + 3) & 3) * 16384, w, lane); \
    else if (h < 3)     dma16(hbn + ((s) - 15) * 8192, lds + ((ph + (s) + 3) & 3) * 16384, w, lane); \
} while (0)

__global__ __launch_bounds__(256, 1)
void edge_kernel(const float* __restrict__ ef, const int* __restrict__ eidx,
                 const short* __restrict__ Kv_all, const short* __restrict__ Vv_all,
                 const short* __restrict__ imgW,
                 const float* __restrict__ lu_b, const float* __restrict__ ln1_g,
                 const float* __restrict__ ln1_b, const float* __restrict__ msg_b,
                 const float* __restrict__ ln2_g, const float* __restrict__ ln2_b,
                 float* __restrict__ out1)
{
    extern __shared__ char lds[];
    const int tid = threadIdx.x;
    const int lane = tid & 63, w = tid >> 6;
    const int l15 = lane & 15, lg = lane >> 4;
    const int e0 = blockIdx.x * 64 + w * 16;
    const int rb = lg * 4;
    char* myscr = lds + 65536 + w * 13312;
    float* bls = (float*)(lds + 118784);
    const float scale = 0.0625f;   // 1/sqrt(2*OUT)

    // ---- prologue: bias tables -> LDS ----
    {
        int j = tid;
        #pragma unroll
        for (int it = 0; it < 4; ++it, j += 256) {
            bls[j] = ln1_g[j]; bls[1024 + j] = ln1_b[j]; bls[2048 + j] = lu_b[j];
        }
        bls[3072 + tid] = msg_b[tid];   bls[3072 + 256 + tid] = msg_b[256 + tid];
        bls[3584 + tid] = ln2_g[tid];   bls[3584 + 256 + tid] = ln2_g[256 + tid];
        bls[4096 + tid] = ln2_b[tid];   bls[4096 + 256 + tid] = ln2_b[256 + tid];
        asm volatile("s_waitcnt lgkmcnt(0)" ::: "memory");
    }

    // ef A-fragments; indices
    const float* efr = ef + (size_t)(e0 + l15) * 128 + lg * 8;
    s16x8 aef[4];
    #pragma unroll
    for (int ks = 0; ks < 4; ++ks) {
        float4 v0 = *(const float4*)(efr + ks * 32);
        float4 v1 = *(const float4*)(efr + ks * 32 + 4);
        s16x8 t;
        t[0] = f2bf(v0.x); t[1] = f2bf(v0.y); t[2] = f2bf(v0.z); t[3] = f2bf(v0.w);
        t[4] = f2bf(v1.x); t[5] = f2bf(v1.y); t[6] = f2bf(v1.z); t[7] = f2bf(v1.w);
        aef[ks] = t;
    }
    const int srcA = eidx[e0 + l15];
    int dstC[4];
    #pragma unroll
    for (int r = 0; r < 4; ++r) dstC[r] = eidx[NE + e0 + rb + r];
    const int gRow = lane >> 2;            // 0..15
    const int gChunk = lane & 3;           // 0..3
    const int dstG = eidx[NE + e0 + gRow];
    const int srcG = eidx[e0 + gRow];

    // issue 16KB chunks 0,1,2 of head 0 into buffers 0,1,2
    dma16(imgW,         lds,          w, lane);
    dma16(imgW + 8192,  lds + 16384,  w, lane);
    dma16(imgW + 16384, lds + 32768,  w, lane);

    f32x4 outc[8];
    #pragma unroll
    for (int nt = 0; nt < 8; ++nt) outc[nt] = (f32x4){0.f, 0.f, 0.f, 0.f};

    for (int h = 0; h < HEADS; ++h) {
        const short* hb  = imgW + h * 147456;
        const short* hbn = imgW + (h + 1) * 147456;   // used only if h < 3
        const int ph = (h & 1) * 2;                   // 18 % 4 == 2 phase shift
        f32x4 accK[8];
        #pragma unroll
        for (int nt = 0; nt < 8; ++nt) accK[nt] = (f32x4){0, 0, 0, 0};
        s16x8 vvr[4];
        unsigned gpk[16][2];

        // ---- s=0..1: KW -> accK (4 tiles per step) ----
        #pragma unroll
        for (int s = 0; s < 2; ++s) {
            STEP_SYNC(s);
            const char* bA = lds + ((ph + s) & 3) * 16384;
            PRIO1();
            #pragma unroll
            for (int ks = 0; ks < 4; ++ks)
                #pragma unroll
                for (int ct = 0; ct < 4; ++ct)
                    accK[s * 4 + ct] = mfma16(aef[ks], B128h(bA, ct, ks), accK[s * 4 + ct]);
            PRIO0();
            if (s == 0) {       // q/k1 gather + per-wave scratch write (padded rows)
                #pragma unroll
                for (int j = 0; j < 4; ++j) {
                    s16x8 qv = *(const s16x8*)(Kv_all + (size_t)dstG * 512 + h * 128 + gChunk * 32 + j * 8);
                    s16x8 kv = *(const s16x8*)(Kv_all + (size_t)srcG * 512 + h * 128 + gChunk * 32 + j * 8);
                    int byte = gRow * 272 + ((((gChunk * 4 + j) * 16)) ^ ((gRow & 7) << 4));
                    *(s16x8*)(myscr + byte) = qv;
                    *(s16x8*)(myscr + 4352 + byte) = kv;
                }
            }
        }

        // ---- s=2..3: VW -> VE scratch (4 tiles per step); s==2: vvr; s==3: LN1 ----
        #pragma unroll
        for (int i = 0; i < 2; ++i) {
            const int s = 2 + i;
            STEP_SYNC(s);
            const char* bA = lds + ((ph + s) & 3) * 16384;
            f32x4 aV[4];
            #pragma unroll
            for (int t = 0; t < 4; ++t) aV[t] = (f32x4){0, 0, 0, 0};
            PRIO1();
            #pragma unroll
            for (int ks = 0; ks < 4; ++ks)
                #pragma unroll
                for (int t = 0; t < 4; ++t)
                    aV[t] = mfma16(aef[ks], B128h(bA, t, ks), aV[t]);
            PRIO0();
            #pragma unroll
            for (int t = 0; t < 4; ++t) {   // VE tiles 4i+t -> scratch @8704, rows x272
                int c = (i * 4 + t) * 16 + l15;
                #pragma unroll
                for (int r = 0; r < 4; ++r) {
                    int row = rb + r;
                    int byte = 8704 + row * 272 + ((c * 2) ^ ((row & 7) << 4));
                    *(short*)(myscr + byte) = f2bf(aV[t][r]);
                }
            }
            if (i == 0) {
                #pragma unroll
                for (int ks = 0; ks < 4; ++ks)
                    vvr[ks] = *(const s16x8*)(Vv_all + (size_t)srcA * 512 + h * 128 + ks * 32 + lg * 8);
            }
            if (i == 1) {
                #pragma unroll
                for (int r = 0; r < 4; ++r) {       // LN1 + sigmoid gate (one-pass)
                    const int i2r = rb + r;
                    const int swz = (i2r & 7) << 4;
                    float al[16];
                    float s1 = 0.f, s2 = 0.f;
                    #pragma unroll
                    for (int nt = 0; nt < 8; ++nt) {
                        int off = i2r * 272 + ((nt * 32 + l15 * 2) ^ swz);
                        float q  = bf2f(*(const short*)(myscr + off));
                        float k1 = bf2f(*(const short*)(myscr + 4352 + off));
                        float alo = q * k1 * scale;
                        float ahi = q * accK[nt][r] * scale;
                        al[nt] = alo; al[nt + 8] = ahi;
                        s1 += alo + ahi; s2 += alo * alo + ahi * ahi;
                    }
                    #pragma unroll
                    for (int m = 1; m < 16; m <<= 1) { s1 += __shfl_xor(s1, m); s2 += __shfl_xor(s2, m); }
                    float mean = s1 * (1.f / 256.f);
                    float var  = s2 * (1.f / 256.f) - mean * mean;
                    float rstd = rsqrtf(var + EPSV);
                    #pragma unroll
                    for (int i2 = 0; i2 < 16; ++i2) {
                        int c = i2 * 16 + l15;
                        float z = (al[i2] - mean) * rstd * bls[h * 256 + c] + bls[1024 + h * 256 + c];
                        float g = 1.f / (1.f + __expf(-z));
                        unsigned gb = (unsigned)(unsigned short)f2bf(g);
                        if ((r & 1) == 0) gpk[i2][r >> 1] = gb;
                        else              gpk[i2][r >> 1] |= gb << 16;
                    }
                }
            }
        }

        // ---- s=4..11: LU (2 m1 tiles per step) -> m1g scratch (rows x528) ----
        #pragma unroll
        for (int c = 0; c < 8; ++c) {
            const int s = 4 + c;
            STEP_SYNC(s);
            const char* bA = lds + ((ph + s) & 3) * 16384;
            #pragma unroll
            for (int tt = 0; tt < 2; ++tt) {
                const int cidx = c * 2 + tt;        // m1 tile 0..15
                f32x4 m1c = (f32x4){0, 0, 0, 0};
                PRIO1();
                #pragma unroll
                for (int ks = 0; ks < 8; ++ks) {
                    s16x8 a;
                    if (ks < 4) a = vvr[ks];
                    else {
                        int byte = 8704 + l15 * 272 + (((((ks - 4) * 32 + lg * 8)) * 2) ^ ((l15 & 7) << 4));
                        a = *(const s16x8*)(myscr + byte);
                    }
                    m1c = mfma16(a, B256h(bA, tt, ks), m1c);
                }
                PRIO0();
                int col = cidx * 16 + l15;
                float bias = bls[2048 + h * 256 + col];
                #pragma unroll
                for (int r = 0; r < 4; ++r) {
                    float g = bf2f((short)((gpk[cidx][r >> 1] >> ((r & 1) * 16)) & 0xFFFFu));
                    int row = rb + r;
                    int byte = row * 528 + ((col * 2) ^ ((row & 7) << 4));
                    *(short*)(myscr + byte) = f2bf((m1c[r] + bias) * g);
                }
            }
        }

        // ---- s=12..15: MSG (2 m2 tiles per step) ----
        f32x4 m2[8];
        #pragma unroll
        for (int nt = 0; nt < 8; ++nt) m2[nt] = (f32x4){0, 0, 0, 0};
        #pragma unroll
        for (int c = 0; c < 4; ++c) {
            const int s = 12 + c;
            STEP_SYNC(s);
            const char* bA = lds + ((ph + s) & 3) * 16384;
            PRIO1();
            #pragma unroll
            for (int ks = 0; ks < 8; ++ks) {
                int byte = l15 * 528 + (((ks * 32 + lg * 8) * 2) ^ ((l15 & 7) << 4));
                s16x8 a = *(const s16x8*)(myscr + byte);
                m2[c * 2]     = mfma16(a, B256h(bA, 0, ks), m2[c * 2]);
                m2[c * 2 + 1] = mfma16(a, B256h(bA, 1, ks), m2[c * 2 + 1]);
            }
            PRIO0();
        }
        {   // LN2 + leaky -> m2 scratch @8704 (rows x272)
            float s1[4] = {0, 0, 0, 0}, s2[4] = {0, 0, 0, 0};
            #pragma unroll
            for (int nt = 0; nt < 8; ++nt) {
                int c = nt * 16 + l15;
                float bias = bls[3072 + h * 128 + c];
                #pragma unroll
                for (int r = 0; r < 4; ++r) {
                    float v = m2[nt][r] + bias;
                    m2[nt][r] = v;
                    s1[r] += v; s2[r] += v * v;
                }
            }
            #pragma unroll
            for (int m = 1; m < 16; m <<= 1)
                #pragma unroll
                for (int r = 0; r < 4; ++r) { s1[r] += __shfl_xor(s1[r], m); s2[r] += __shfl_xor(s2[r], m); }
            float mean[4], rstd[4];
            #pragma unroll
            for (int r = 0; r < 4; ++r) {
                mean[r] = s1[r] * (1.f / 128.f);
                float var = s2[r] * (1.f / 128.f) - mean[r] * mean[r];
                rstd[r] = rsqrtf(var + EPSV);
            }
            #pragma unroll
            for (int nt = 0; nt < 8; ++nt) {
                int c = nt * 16 + l15;
                float g2 = bls[3584 + h * 128 + c], b2 = bls[4096 + h * 128 + c];
                #pragma unroll
                for (int r = 0; r < 4; ++r) {
                    float v = (m2[nt][r] - mean[r]) * rstd[r] * g2 + b2;
                    v = v > 0.f ? v : v * NEGS;
                    int row = rb + r;
                    int byte = 8704 + row * 272 + ((c * 2) ^ ((row & 7) << 4));
                    *(short*)(myscr + byte) = f2bf(v);
                }
            }
        }

        // ---- s=16..17: CAT (4 tiles per step) -> outc ----
        #pragma unroll
        for (int c = 0; c < 2; ++c) {
            const int s = 16 + c;
            STEP_SYNC(s);
            const char* bA = lds + ((ph + s) & 3) * 16384;
            PRIO1();
            #pragma unroll
            for (int ks = 0; ks < 4; ++ks) {
                int byte = 8704 + l15 * 272 + (((ks * 32 + lg * 8) * 2) ^ ((l15 & 7) << 4));
                s16x8 a = *(const s16x8*)(myscr + byte);
                #pragma unroll
                for (int ct = 0; ct < 4; ++ct)
                    outc[c * 4 + ct] = mfma16(a, B128h(bA, ct, ks), outc[c * 4 + ct]);
            }
            PRIO0();
        }
    }

    // ---- scatter: one 128-wide atomic add per edge ----
    #pragma unroll
    for (int nt = 0; nt < 8; ++nt) {
        int c = nt * 16 + l15;
        #pragma unroll
        for (int r = 0; r < 4; ++r)
            atomicAdd(out1 + (size_t)dstC[r] * 128 + c, outc[nt][r]);
    }
}

// ---------------- BN statistics ----------------
__global__ void bn_stats(const float* __restrict__ out1, const float* __restrict__ cat_b,
                         float* __restrict__ stats)
{
    const int col = threadIdx.x;
    const int r0 = blockIdx.x * 128;
    const float cb = cat_b[col];
    float s = 0.f, s2 = 0.f;
    for (int i = 0; i < 128; ++i) {
        int row = r0 + i;
        if (row < NN) {
            float v = out1[(size_t)row * 128 + col] + cb;
            s += v; s2 += v * v;
        }
    }
    atomicAdd(stats + col, s);
    atomicAdd(stats + 128 + col, s2);
}

// ---------------- finalize: BN + leaky + residual ----------------
__global__ void finalize(const float* __restrict__ out1, const float* __restrict__ resid,
                         const float* __restrict__ stats, const float* __restrict__ cat_b,
                         const float* __restrict__ bn_g, const float* __restrict__ bn_b,
                         const float* __restrict__ inp_b, float* __restrict__ out)
{
    int i = blockIdx.x * 256 + threadIdx.x;
    if (i >= NN * 128) return;
    int col = i & 127;
    float mu = stats[col] * (1.f / NN);
    float var = stats[128 + col] * (1.f / NN) - mu * mu;
    float rstd = rsqrtf(var + EPSV);
    float v = out1[i] + cat_b[col];
    v = (v - mu) * rstd * bn_g[col] + bn_b[col];
    v = v > 0.f ? v : v * NEGS;
    out[i] = v + resid[i] + inp_b[col];
}

extern "C" void kernel_launch(void* const* d_in, const int* in_sizes, int n_in,
                              void* d_out, int out_size, void* d_ws, size_t ws_size,
                              hipStream_t stream)
{
    (void)in_sizes; (void)n_in; (void)out_size; (void)ws_size;
    const float* x     = (const float*)d_in[0];
    const int*   eidx  = (const int*)d_in[1];
    const float* ef    = (const float*)d_in[2];
    const float* Kv2v  = (const float*)d_in[3];
    const float* Ke2v  = (const float*)d_in[4];
    const float* Vv2v  = (const float*)d_in[5];
    const float* Ve2v  = (const float*)d_in[6];
    const float* lu_W  = (const float*)d_in[7];
    const float* lu_b  = (const float*)d_in[8];
    const float* ln1_g = (const float*)d_in[9];
    const float* ln1_b = (const float*)d_in[10];
    const float* msg_W = (const float*)d_in[11];
    const float* msg_b = (const float*)d_in[12];
    const float* ln2_g = (const float*)d_in[13];
    const float* ln2_b = (const float*)d_in[14];
    const float* cat_W = (const float*)d_in[15];
    const float* cat_b = (const float*)d_in[16];
    const float* inp_W = (const float*)d_in[17];
    const float* inp_b = (const float*)d_in[18];
    const float* bn_g  = (const float*)d_in[19];
    const float* bn_b  = (const float*)d_in[20];

    char* ws = (char*)d_ws;
    short* nodeW_t = (short*)(ws + 0);          // 294912
    short* imgW    = (short*)(ws + 294912);     // 1179648 (4 heads x 294912)
    short* Kv_all  = (short*)(ws + 1474560);    // 51,200,000
    short* Vv_all  = (short*)(ws + 52674560);   // 51,200,000
    float* resid   = (float*)(ws + 103874560);  // 25,600,000
    float* out1    = (float*)(ws + 129474560);  // 25,600,000
    float* stats   = (float*)(ws + 155074560);  // 1024

    hipFuncSetAttribute((const void*)edge_kernel,
                        hipFuncAttributeMaxDynamicSharedMemorySize, 137216);

    hipMemsetAsync(out1, 0, 25600000 + 1024, stream);   // out1 + stats (contiguous)
    prep_weights<<<2880, 256, 0, stream>>>(Kv2v, Vv2v, inp_W, Ke2v, Ve2v, lu_W, msg_W, cat_W,
                                           nodeW_t, imgW);
    node_proj<<<782, 256, 0, stream>>>(x, nodeW_t, Kv_all, Vv_all, resid);
    edge_kernel<<<3125, 256, 137216, stream>>>(ef, eidx, Kv_all, Vv_all, imgW,
                                               lu_b, ln1_g, ln1_b, msg_b,
                                               ln2_g, ln2_b, out1);
    bn_stats<<<391, 128, 0, stream>>>(out1, cat_b, stats);
    finalize<<<25000, 256, 0, stream>>>(out1, resid, stats, cat_b, bn_g, bn_b, inp_b,
                                        (float*)d_out);
}

// Round 18
// 1341.967 us; speedup vs baseline: 1.0658x; 1.0658x over previous
//
#include <hip/hip_runtime.h>
#include <hip/hip_bf16.h>

#define NN 50000
#define NE 200000
#define HEADS 4
#define EPSV 1e-5f
#define NEGS 0.01f

using f32x4 = __attribute__((ext_vector_type(4))) float;
using s16x8 = __attribute__((ext_vector_type(8))) short;
using bf16x8 = __attribute__((ext_vector_type(8))) __bf16;

__device__ __forceinline__ short f2bf(float f) {
    union { float f; unsigned u; } v; v.f = f;
    unsigned r = v.u + 0x7FFFu + ((v.u >> 16) & 1u);
    return (short)(r >> 16);
}
__device__ __forceinline__ float bf2f(short s) {
    union { unsigned u; float f; } v; v.u = ((unsigned)(unsigned short)s) << 16;
    return v.f;
}
__device__ __forceinline__ f32x4 mfma16(s16x8 a, s16x8 b, f32x4 c) {
    return __builtin_amdgcn_mfma_f32_16x16x32_bf16(
        __builtin_bit_cast(bf16x8, a), __builtin_bit_cast(bf16x8, b), c, 0, 0, 0);
}
__device__ __forceinline__ void gld16(const void* g, void* l) {
    __builtin_amdgcn_global_load_lds(
        (const __attribute__((address_space(1))) void*)g,
        (__attribute__((address_space(3))) void*)l, 16, 0, 0);
}
// DMA one 8KB chunk (4096 shorts) image -> LDS, 256 threads, 2 ops each
__device__ __forceinline__ void dma8(const short* src, char* dst, int w, int lane) {
    gld16(src + w * 512 + lane * 8,        dst + w * 1024);
    gld16(src + 2048 + w * 512 + lane * 8, dst + 4096 + w * 1024);
}

// ---------------- weight prep (unchanged, verified) ----------------
// imgW per-head = 36 contiguous 4096-short (8KB) chunks:
//   KW: 0-3, VW: 4-7, LU: 8-23, MSG: 24-31, CAT: 32-35.
__global__ void prep_weights(const float* __restrict__ Kv2v, const float* __restrict__ Vv2v,
                             const float* __restrict__ inpW,
                             const float* __restrict__ Ke2v, const float* __restrict__ Ve2v,
                             const float* __restrict__ luW, const float* __restrict__ msgW,
                             const float* __restrict__ catW,
                             short* __restrict__ nodeW_t, short* __restrict__ imgW)
{
    int i = blockIdx.x * 256 + threadIdx.x;
    if (i < 147456) {                       // nodeW_t [1152][128]
        int j = i >> 7, k = i & 127;
        float v;
        if (j < 512)       v = Kv2v[(j >> 7) * 16384 + k * 128 + (j & 127)];
        else if (j < 1024) v = Vv2v[((j - 512) >> 7) * 16384 + k * 128 + (j & 127)];
        else               v = inpW[k * 128 + (j - 1024)];
        nodeW_t[i] = f2bf(v);
        return;
    }
    i -= 147456;
    if (i >= 589824) return;
    int h = i / 147456;
    int r = i % 147456;
    short* img = imgW + h * 147456;
    if (r < 16384) {                        // KW (K=128)
        int colc = r >> 7, k = r & 127;
        img[(colc * 128 + k) ^ ((colc & 7) << 3)] = f2bf(Ke2v[h * 16384 + k * 128 + colc]);
    } else if (r < 32768) {                 // VW (K=128)
        int e = r - 16384; int colc = e >> 7, k = e & 127;
        img[16384 + ((colc * 128 + k) ^ ((colc & 7) << 3))] = f2bf(Ve2v[h * 16384 + k * 128 + colc]);
    } else if (r < 98304) {                 // LU (K=256)
        int e = r - 32768; int c = e >> 14, ec = e & 16383;
        int colc = ec >> 8, k = ec & 255; int col = c * 64 + colc;
        img[32768 + c * 16384 + ((colc * 256 + k) ^ ((colc & 7) << 3))] =
            f2bf(luW[h * 65536 + k * 256 + col]);
    } else if (r < 131072) {                // MSG (K=256)
        int e = r - 98304; int c = e >> 14, ec = e & 16383;
        int colc = ec >> 8, k = ec & 255; int col = c * 64 + colc;
        img[98304 + c * 16384 + ((colc * 256 + k) ^ ((colc & 7) << 3))] =
            f2bf(msgW[h * 32768 + k * 128 + col]);
    } else {                                // CAT (K=128)
        int e = r - 131072; int colc = e >> 7, k = e & 127;
        img[131072 + ((colc * 128 + k) ^ ((colc & 7) << 3))] =
            f2bf(catW[(h * 128 + k) * 128 + colc]);
    }
}

// ---------------- node projections (unchanged, verified) ----------------
__global__ __launch_bounds__(256, 2)
void node_proj(const float* __restrict__ x, const short* __restrict__ nodeW_t,
               short* __restrict__ Kv_all, short* __restrict__ Vv_all,
               float* __restrict__ resid)
{
    __shared__ alignas(16) short xt[64 * 128];
    const int tid = threadIdx.x;
    const int row0 = blockIdx.x * 64;
    #pragma unroll
    for (int it = 0; it < 8; ++it) {
        int idx4 = it * 256 + tid;
        int r = idx4 >> 5;
        int c = (idx4 & 31) * 4;
        float4 v = {0.f, 0.f, 0.f, 0.f};
        if (row0 + r < NN) v = *(const float4*)(x + (size_t)(row0 + r) * 128 + c);
        short4 sw; sw.x = f2bf(v.x); sw.y = f2bf(v.y); sw.z = f2bf(v.z); sw.w = f2bf(v.w);
        int byte = (r * 256 + c * 2) ^ ((r & 7) << 4);
        *(short4*)((char*)xt + byte) = sw;
    }
    __syncthreads();
    const int lane = tid & 63, w = tid >> 6;
    const int l15 = lane & 15, lg = lane >> 4;
    const int rloc = w * 16 + l15;
    s16x8 a[4];
    #pragma unroll
    for (int ks = 0; ks < 4; ++ks) {
        int byte = (rloc * 256 + (ks * 32 + lg * 8) * 2) ^ ((rloc & 7) << 4);
        a[ks] = *(const s16x8*)((const char*)xt + byte);
    }
    const int rowC = row0 + w * 16 + lg * 4;
    for (int nc = 0; nc < 18; ++nc) {
        f32x4 acc[4];
        s16x8 b[16];
        #pragma unroll
        for (int q = 0; q < 4; ++q) {
            acc[q] = (f32x4){0.f, 0.f, 0.f, 0.f};
            int j = (nc * 4 + q) * 16 + l15;
            #pragma unroll
            for (int ks = 0; ks < 4; ++ks)
                b[q * 4 + ks] = *(const s16x8*)(nodeW_t + j * 128 + ks * 32 + lg * 8);
        }
        #pragma unroll
        for (int q = 0; q < 4; ++q)
            #pragma unroll
            for (int ks = 0; ks < 4; ++ks)
                acc[q] = mfma16(a[ks], b[q * 4 + ks], acc[q]);
        #pragma unroll
        for (int q = 0; q < 4; ++q) {
            int j = (nc * 4 + q) * 16 + l15;
            #pragma unroll
            for (int r = 0; r < 4; ++r) {
                int row = rowC + r;
                if (row >= NN) continue;
                if (j < 512)       Kv_all[(size_t)row * 512 + j] = f2bf(acc[q][r]);
                else if (j < 1024) Vv_all[(size_t)row * 512 + (j - 512)] = f2bf(acc[q][r]);
                else               resid[(size_t)row * 128 + (j - 1024)] = acc[q][r];
            }
        }
    }
}

// ---------------- fused edge pipeline: R12 base (verified 1208us) + dual-chain MFMA ----------------
// Dynamic LDS 100352:
//   wbuf[4] @ 0..32767 (4 x 8KB, rotate chunk%4; 36%4==0 so stable per head)
//   per-wave scratch @32768 + w*12288 (q@0, k1@4096, VE/m2@8192, m1g@0 overlay)
//   bias tables @81920 (floats)
// Per step: [WAITV(4) counted][s_barrier][issue chunk p+3][compute chunk p].
// Change vs R12: LU/MSG 8-deep serial MFMA chains split into 2 independent
// 4-deep chains (regs-fed + LDS-fed) summed at the end — halves dependent
// MFMA latency on the critical path of 96/144 steps.
#define B128h(buf, ct, ks) \
    (*(const s16x8*)((const short*)(buf) + (((((ct) * 16 + l15) * 128) + (ks) * 32 + lg * 8) ^ ((l15 & 7) << 3))))
#define B256h(buf, ks) \
    (*(const s16x8*)((const short*)(buf) + ((l15 * 256 + (ks) * 32 + lg * 8) ^ ((l15 & 7) << 3))))
#define WAITV(N) asm volatile("s_waitcnt vmcnt(" #N ")" ::: "memory")
#define SBAR() do { __builtin_amdgcn_s_barrier(); __builtin_amdgcn_sched_barrier(0); } while (0)
#define PRIO1() __builtin_amdgcn_s_setprio(1)
#define PRIO0() __builtin_amdgcn_s_setprio(0)

__global__ __launch_bounds__(256, 1)
void edge_kernel(const float* __restrict__ ef, const int* __restrict__ eidx,
                 const short* __restrict__ Kv_all, const short* __restrict__ Vv_all,
                 const short* __restrict__ imgW,
                 const float* __restrict__ lu_b, const float* __restrict__ ln1_g,
                 const float* __restrict__ ln1_b, const float* __restrict__ msg_b,
                 const float* __restrict__ ln2_g, const float* __restrict__ ln2_b,
                 float* __restrict__ out1)
{
    extern __shared__ char lds[];
    const int tid = threadIdx.x;
    const int lane = tid & 63, w = tid >> 6;
    const int l15 = lane & 15, lg = lane >> 4;
    const int e0 = blockIdx.x * 64 + w * 16;
    const int rb = lg * 4;
    char* myscr = lds + 32768 + w * 12288;
    float* bls = (float*)(lds + 81920);
    const float scale = 0.0625f;   // 1/sqrt(2*OUT)

    // ---- prologue: bias tables -> LDS ----
    {
        int j = tid;
        #pragma unroll
        for (int it = 0; it < 4; ++it, j += 256) {
            bls[j] = ln1_g[j]; bls[1024 + j] = ln1_b[j]; bls[2048 + j] = lu_b[j];
        }
        bls[3072 + tid] = msg_b[tid];       bls[3072 + 256 + tid] = msg_b[256 + tid];
        bls[3584 + tid] = ln2_g[tid];       bls[3584 + 256 + tid] = ln2_g[256 + tid];
        bls[4096 + tid] = ln2_b[tid];       bls[4096 + 256 + tid] = ln2_b[256 + tid];
        asm volatile("s_waitcnt lgkmcnt(0)" ::: "memory");
    }

    // ef A-fragments; indices
    const float* efr = ef + (size_t)(e0 + l15) * 128 + lg * 8;
    s16x8 aef[4];
    #pragma unroll
    for (int ks = 0; ks < 4; ++ks) {
        float4 v0 = *(const float4*)(efr + ks * 32);
        float4 v1 = *(const float4*)(efr + ks * 32 + 4);
        s16x8 t;
        t[0] = f2bf(v0.x); t[1] = f2bf(v0.y); t[2] = f2bf(v0.z); t[3] = f2bf(v0.w);
        t[4] = f2bf(v1.x); t[5] = f2bf(v1.y); t[6] = f2bf(v1.z); t[7] = f2bf(v1.w);
        aef[ks] = t;
    }
    const int srcA = eidx[e0 + l15];
    int dstC[4];
    #pragma unroll
    for (int r = 0; r < 4; ++r) dstC[r] = eidx[NE + e0 + rb + r];
    const int gRow = lane >> 2;            // 0..15
    const int gChunk = lane & 3;           // 0..3
    const int dstG = eidx[NE + e0 + gRow];
    const int srcG = eidx[e0 + gRow];

    // issue chunks 0,1,2 of head 0
    dma8(imgW,        lds,         w, lane);
    dma8(imgW + 4096, lds + 8192,  w, lane);
    dma8(imgW + 8192, lds + 16384, w, lane);

    f32x4 outc[8];
    #pragma unroll
    for (int nt = 0; nt < 8; ++nt) outc[nt] = (f32x4){0.f, 0.f, 0.f, 0.f};

    for (int h = 0; h < HEADS; ++h) {
        const short* hb = imgW + h * 147456;
        f32x4 accK[8];
        #pragma unroll
        for (int nt = 0; nt < 8; ++nt) accK[nt] = (f32x4){0, 0, 0, 0};
        s16x8 vvr[4];
        unsigned gpk[16][2];

        // ---- p=0..3: KW chunks -> accK ----
        #pragma unroll
        for (int p = 0; p < 4; ++p) {
            WAITV(4); SBAR();
            dma8(hb + (p + 3) * 4096, lds + ((p + 3) & 3) * 8192, w, lane);
            const char* bA = lds + (p & 3) * 8192;
            PRIO1();
            #pragma unroll
            for (int ks = 0; ks < 4; ++ks) {
                accK[p * 2]     = mfma16(aef[ks], B128h(bA, 0, ks), accK[p * 2]);
                accK[p * 2 + 1] = mfma16(aef[ks], B128h(bA, 1, ks), accK[p * 2 + 1]);
            }
            PRIO0();
            if (p == 0) {       // q/k1 gather + per-wave scratch write
                #pragma unroll
                for (int j = 0; j < 4; ++j) {
                    s16x8 qv = *(const s16x8*)(Kv_all + (size_t)dstG * 512 + h * 128 + gChunk * 32 + j * 8);
                    s16x8 kv = *(const s16x8*)(Kv_all + (size_t)srcG * 512 + h * 128 + gChunk * 32 + j * 8);
                    int byte = gRow * 256 + ((((gChunk * 4 + j) * 16)) ^ ((gRow & 7) << 4));
                    *(s16x8*)(myscr + byte) = qv;
                    *(s16x8*)(myscr + 4096 + byte) = kv;
                }
            }
        }

        // ---- p=4..7: VW chunks -> VE scratch; p==4: vvr; p==7: LN1+gate ----
        #pragma unroll
        for (int i = 0; i < 4; ++i) {
            const int p = 4 + i;
            WAITV(4); SBAR();
            dma8(hb + (p + 3) * 4096, lds + ((p + 3) & 3) * 8192, w, lane);
            const char* bA = lds + (p & 3) * 8192;
            f32x4 aV0 = (f32x4){0, 0, 0, 0}, aV1 = (f32x4){0, 0, 0, 0};
            PRIO1();
            #pragma unroll
            for (int ks = 0; ks < 4; ++ks) {
                aV0 = mfma16(aef[ks], B128h(bA, 0, ks), aV0);
                aV1 = mfma16(aef[ks], B128h(bA, 1, ks), aV1);
            }
            PRIO0();
            #pragma unroll
            for (int t = 0; t < 2; ++t) {
                f32x4 av = t ? aV1 : aV0;
                int c = (i * 2 + t) * 16 + l15;
                #pragma unroll
                for (int r = 0; r < 4; ++r) {
                    int row = rb + r;
                    int byte = 8192 + ((row * 256 + c * 2) ^ ((row & 7) << 4));
                    *(short*)(myscr + byte) = f2bf(av[r]);
                }
            }
            if (i == 0) {
                #pragma unroll
                for (int ks = 0; ks < 4; ++ks)
                    vvr[ks] = *(const s16x8*)(Vv_all + (size_t)srcA * 512 + h * 128 + ks * 32 + lg * 8);
            }
            if (i == 3) {
                #pragma unroll
                for (int r = 0; r < 4; ++r) {       // LN1 + sigmoid gate (verified)
                    const int i2r = rb + r;
                    const int swz = (i2r & 7) << 4;
                    float al[16];
                    float s1 = 0.f, s2 = 0.f;
                    #pragma unroll
                    for (int nt = 0; nt < 8; ++nt) {
                        int off = (i2r * 256 + nt * 32 + l15 * 2) ^ swz;
                        float q  = bf2f(*(const short*)(myscr + off));
                        float k1 = bf2f(*(const short*)(myscr + 4096 + off));
                        float alo = q * k1 * scale;
                        float ahi = q * accK[nt][r] * scale;
                        al[nt] = alo; al[nt + 8] = ahi;
                        s1 += alo + ahi; s2 += alo * alo + ahi * ahi;
                    }
                    #pragma unroll
                    for (int m = 1; m < 16; m <<= 1) { s1 += __shfl_xor(s1, m); s2 += __shfl_xor(s2, m); }
                    float mean = s1 * (1.f / 256.f);
                    float var  = s2 * (1.f / 256.f) - mean * mean;
                    float rstd = rsqrtf(var + EPSV);
                    #pragma unroll
                    for (int i2 = 0; i2 < 16; ++i2) {
                        int c = i2 * 16 + l15;
                        float z = (al[i2] - mean) * rstd * bls[h * 256 + c] + bls[1024 + h * 256 + c];
                        float g = 1.f / (1.f + __expf(-z));
                        unsigned gb = (unsigned)(unsigned short)f2bf(g);
                        if ((r & 1) == 0) gpk[i2][r >> 1] = gb;
                        else              gpk[i2][r >> 1] |= gb << 16;
                    }
                }
            }
        }

        // ---- p=8..23: LU chunks, one m1 tile per step (DUAL 4-deep chains) ----
        #pragma unroll
        for (int c = 0; c < 16; ++c) {
            const int p = 8 + c;
            WAITV(4); SBAR();
            dma8(hb + (p + 3) * 4096, lds + ((p + 3) & 3) * 8192, w, lane);
            const char* bA = lds + (p & 3) * 8192;
            f32x4 m1a = (f32x4){0, 0, 0, 0}, m1b = (f32x4){0, 0, 0, 0};
            PRIO1();
            #pragma unroll
            for (int ks = 0; ks < 4; ++ks) {
                // chain A: register-fed (Vv half)
                m1a = mfma16(vvr[ks], B256h(bA, ks), m1a);
                // chain B: LDS-fed (VE half) — independent accumulator
                int byte = 8192 + ((l15 * 256 + (ks * 32 + lg * 8) * 2) ^ ((l15 & 7) << 4));
                s16x8 a = *(const s16x8*)(myscr + byte);
                m1b = mfma16(a, B256h(bA, ks + 4), m1b);
            }
            PRIO0();
            {
                int col = c * 16 + l15;
                float bias = bls[2048 + h * 256 + col];
                #pragma unroll
                for (int r = 0; r < 4; ++r) {
                    float g = bf2f((short)((gpk[c][r >> 1] >> ((r & 1) * 16)) & 0xFFFFu));
                    int row = rb + r;
                    int byte = (row * 512 + col * 2) ^ ((row & 7) << 4);
                    *(short*)(myscr + byte) = f2bf((m1a[r] + m1b[r] + bias) * g);
                }
            }
        }

        // ---- p=24..31: MSG chunks -> m2 regs (DUAL 4-deep chains) ----
        f32x4 m2[8];
        #pragma unroll
        for (int nt = 0; nt < 8; ++nt) m2[nt] = (f32x4){0, 0, 0, 0};
        #pragma unroll
        for (int c = 0; c < 8; ++c) {
            const int p = 24 + c;
            WAITV(4); SBAR();
            dma8(hb + (p + 3) * 4096, lds + ((p + 3) & 3) * 8192, w, lane);
            const char* bA = lds + (p & 3) * 8192;
            f32x4 mba = (f32x4){0, 0, 0, 0}, mbb = (f32x4){0, 0, 0, 0};
            PRIO1();
            #pragma unroll
            for (int ks = 0; ks < 4; ++ks) {
                int byteA = (l15 * 512 + (ks * 32 + lg * 8) * 2) ^ ((l15 & 7) << 4);
                s16x8 aA = *(const s16x8*)(myscr + byteA);
                mba = mfma16(aA, B256h(bA, ks), mba);
                int byteB = (l15 * 512 + ((ks + 4) * 32 + lg * 8) * 2) ^ ((l15 & 7) << 4);
                s16x8 aB = *(const s16x8*)(myscr + byteB);
                mbb = mfma16(aB, B256h(bA, ks + 4), mbb);
            }
            PRIO0();
            #pragma unroll
            for (int r = 0; r < 4; ++r) m2[c][r] = mba[r] + mbb[r];
        }
        {   // LN2 + leaky -> m2 scratch @8192 (verified)
            float s1[4] = {0, 0, 0, 0}, s2[4] = {0, 0, 0, 0};
            #pragma unroll
            for (int nt = 0; nt < 8; ++nt) {
                int c = nt * 16 + l15;
                float bias = bls[3072 + h * 128 + c];
                #pragma unroll
                for (int r = 0; r < 4; ++r) {
                    float v = m2[nt][r] + bias;
                    m2[nt][r] = v;
                    s1[r] += v; s2[r] += v * v;
                }
            }
            #pragma unroll
            for (int m = 1; m < 16; m <<= 1)
                #pragma unroll
                for (int r = 0; r < 4; ++r) { s1[r] += __shfl_xor(s1[r], m); s2[r] += __shfl_xor(s2[r], m); }
            float mean[4], rstd[4];
            #pragma unroll
            for (int r = 0; r < 4; ++r) {
                mean[r] = s1[r] * (1.f / 128.f);
                float var = s2[r] * (1.f / 128.f) - mean[r] * mean[r];
                rstd[r] = rsqrtf(var + EPSV);
            }
            #pragma unroll
            for (int nt = 0; nt < 8; ++nt) {
                int c = nt * 16 + l15;
                float g2 = bls[3584 + h * 128 + c], b2 = bls[4096 + h * 128 + c];
                #pragma unroll
                for (int r = 0; r < 4; ++r) {
                    float v = (m2[nt][r] - mean[r]) * rstd[r] * g2 + b2;
                    v = v > 0.f ? v : v * NEGS;
                    int row = rb + r;
                    int byte = 8192 + ((row * 256 + c * 2) ^ ((row & 7) << 4));
                    *(short*)(myscr + byte) = f2bf(v);
                }
            }
        }

        // ---- p=32..35: CAT chunks -> outc; prefetch crosses into next head ----
        #pragma unroll
        for (int c = 0; c < 4; ++c) {
            const int p = 32 + c;
            if (p < 34)      { WAITV(4); }
            else if (p == 34) { if (h < 3) { WAITV(4); } else { WAITV(2); } }
            else              { if (h < 3) { WAITV(4); } else { WAITV(0); } }
            SBAR();
            const int t = p + 3;            // 35,36,37,38
            if (t < 36) {
                dma8(hb + t * 4096, lds + (t & 3) * 8192, w, lane);
            } else if (h < 3) {
                dma8(imgW + (h + 1) * 147456 + (t - 36) * 4096, lds + (t & 3) * 8192, w, lane);
            }
            const char* bA = lds + (p & 3) * 8192;
            PRIO1();
            #pragma unroll
            for (int ks = 0; ks < 4; ++ks) {
                int byte = 8192 + ((l15 * 256 + (ks * 32 + lg * 8) * 2) ^ ((l15 & 7) << 4));
                s16x8 a = *(const s16x8*)(myscr + byte);
                outc[c * 2]     = mfma16(a, B128h(bA, 0, ks), outc[c * 2]);
                outc[c * 2 + 1] = mfma16(a, B128h(bA, 1, ks), outc[c * 2 + 1]);
            }
            PRIO0();
        }
    }

    // ---- scatter: one 128-wide atomic add per edge ----
    #pragma unroll
    for (int nt = 0; nt < 8; ++nt) {
        int c = nt * 16 + l15;
        #pragma unroll
        for (int r = 0; r < 4; ++r)
            atomicAdd(out1 + (size_t)dstC[r] * 128 + c, outc[nt][r]);
    }
}

// ---------------- BN statistics ----------------
__global__ void bn_stats(const float* __restrict__ out1, const float* __restrict__ cat_b,
                         float* __restrict__ stats)
{
    const int col = threadIdx.x;
    const int r0 = blockIdx.x * 128;
    const float cb = cat_b[col];
    float s = 0.f, s2 = 0.f;
    for (int i = 0; i < 128; ++i) {
        int row = r0 + i;
        if (row < NN) {
            float v = out1[(size_t)row * 128 + col] + cb;
            s += v; s2 += v * v;
        }
    }
    atomicAdd(stats + col, s);
    atomicAdd(stats + 128 + col, s2);
}

// ---------------- finalize: BN + leaky + residual ----------------
__global__ void finalize(const float* __restrict__ out1, const float* __restrict__ resid,
                         const float* __restrict__ stats, const float* __restrict__ cat_b,
                         const float* __restrict__ bn_g, const float* __restrict__ bn_b,
                         const float* __restrict__ inp_b, float* __restrict__ out)
{
    int i = blockIdx.x * 256 + threadIdx.x;
    if (i >= NN * 128) return;
    int col = i & 127;
    float mu = stats[col] * (1.f / NN);
    float var = stats[128 + col] * (1.f / NN) - mu * mu;
    float rstd = rsqrtf(var + EPSV);
    float v = out1[i] + cat_b[col];
    v = (v - mu) * rstd * bn_g[col] + bn_b[col];
    v = v > 0.f ? v : v * NEGS;
    out[i] = v + resid[i] + inp_b[col];
}

extern "C" void kernel_launch(void* const* d_in, const int* in_sizes, int n_in,
                              void* d_out, int out_size, void* d_ws, size_t ws_size,
                              hipStream_t stream)
{
    (void)in_sizes; (void)n_in; (void)out_size; (void)ws_size;
    const float* x     = (const float*)d_in[0];
    const int*   eidx  = (const int*)d_in[1];
    const float* ef    = (const float*)d_in[2];
    const float* Kv2v  = (const float*)d_in[3];
    const float* Ke2v  = (const float*)d_in[4];
    const float* Vv2v  = (const float*)d_in[5];
    const float* Ve2v  = (const float*)d_in[6];
    const float* lu_W  = (const float*)d_in[7];
    const float* lu_b  = (const float*)d_in[8];
    const float* ln1_g = (const float*)d_in[9];
    const float* ln1_b = (const float*)d_in[10];
    const float* msg_W = (const float*)d_in[11];
    const float* msg_b = (const float*)d_in[12];
    const float* ln2_g = (const float*)d_in[13];
    const float* ln2_b = (const float*)d_in[14];
    const float* cat_W = (const float*)d_in[15];
    const float* cat_b = (const float*)d_in[16];
    const float* inp_W = (const float*)d_in[17];
    const float* inp_b = (const float*)d_in[18];
    const float* bn_g  = (const float*)d_in[19];
    const float* bn_b  = (const float*)d_in[20];

    char* ws = (char*)d_ws;
    short* nodeW_t = (short*)(ws + 0);          // 294912
    short* imgW    = (short*)(ws + 294912);     // 1179648 (4 heads x 294912)
    short* Kv_all  = (short*)(ws + 1474560);    // 51,200,000
    short* Vv_all  = (short*)(ws + 52674560);   // 51,200,000
    float* resid   = (float*)(ws + 103874560);  // 25,600,000
    float* out1    = (float*)(ws + 129474560);  // 25,600,000
    float* stats   = (float*)(ws + 155074560);  // 1024

    hipFuncSetAttribute((const void*)edge_kernel,
                        hipFuncAttributeMaxDynamicSharedMemorySize, 100352);

    hipMemsetAsync(out1, 0, 25600000 + 1024, stream);   // out1 + stats (contiguous)
    prep_weights<<<2880, 256, 0, stream>>>(Kv2v, Vv2v, inp_W, Ke2v, Ve2v, lu_W, msg_W, cat_W,
                                           nodeW_t, imgW);
    node_proj<<<782, 256, 0, stream>>>(x, nodeW_t, Kv_all, Vv_all, resid);
    edge_kernel<<<3125, 256, 100352, stream>>>(ef, eidx, Kv_all, Vv_all, imgW,
                                               lu_b, ln1_g, ln1_b, msg_b,
                                               ln2_g, ln2_b, out1);
    bn_stats<<<391, 128, 0, stream>>>(out1, cat_b, stats);
    finalize<<<25000, 256, 0, stream>>>(out1, resid, stats, cat_b, bn_g, bn_b, inp_b,
                                        (float*)d_out);
}

// Round 19
// 1310.936 us; speedup vs baseline: 1.0911x; 1.0237x over previous
//
#include <hip/hip_runtime.h>
#include <hip/hip_bf16.h>

#define NN 50000
#define NE 200000
#define HEADS 4
#define EPSV 1e-5f
#define NEGS 0.01f

using f32x4 = __attribute__((ext_vector_type(4))) float;
using s16x8 = __attribute__((ext_vector_type(8))) short;
using bf16x8 = __attribute__((ext_vector_type(8))) __bf16;

// native bf16 convert: compiles to the hw cvt op (RNE), ~1 VALU vs ~5 for the
// hand-rolled union version (guide m240: scalar cast is the fast path)
__device__ __forceinline__ short f2bf(float f) {
    __bf16 b = (__bf16)f;
    return __builtin_bit_cast(short, b);
}
__device__ __forceinline__ float bf2f(short s) {
    union { unsigned u; float f; } v; v.u = ((unsigned)(unsigned short)s) << 16;
    return v.f;
}
__device__ __forceinline__ f32x4 mfma16(s16x8 a, s16x8 b, f32x4 c) {
    return __builtin_amdgcn_mfma_f32_16x16x32_bf16(
        __builtin_bit_cast(bf16x8, a), __builtin_bit_cast(bf16x8, b), c, 0, 0, 0);
}
__device__ __forceinline__ void gld16(const void* g, void* l) {
    __builtin_amdgcn_global_load_lds(
        (const __attribute__((address_space(1))) void*)g,
        (__attribute__((address_space(3))) void*)l, 16, 0, 0);
}
// DMA one 8KB chunk (4096 shorts) image -> LDS, 256 threads, 2 ops each
__device__ __forceinline__ void dma8(const short* src, char* dst, int w, int lane) {
    gld16(src + w * 512 + lane * 8,        dst + w * 1024);
    gld16(src + 2048 + w * 512 + lane * 8, dst + 4096 + w * 1024);
}

// ---------------- weight prep (unchanged, verified) ----------------
// imgW per-head = 36 contiguous 4096-short (8KB) chunks:
//   KW: 0-3, VW: 4-7, LU: 8-23, MSG: 24-31, CAT: 32-35.
__global__ void prep_weights(const float* __restrict__ Kv2v, const float* __restrict__ Vv2v,
                             const float* __restrict__ inpW,
                             const float* __restrict__ Ke2v, const float* __restrict__ Ve2v,
                             const float* __restrict__ luW, const float* __restrict__ msgW,
                             const float* __restrict__ catW,
                             short* __restrict__ nodeW_t, short* __restrict__ imgW)
{
    int i = blockIdx.x * 256 + threadIdx.x;
    if (i < 147456) {                       // nodeW_t [1152][128]
        int j = i >> 7, k = i & 127;
        float v;
        if (j < 512)       v = Kv2v[(j >> 7) * 16384 + k * 128 + (j & 127)];
        else if (j < 1024) v = Vv2v[((j - 512) >> 7) * 16384 + k * 128 + (j & 127)];
        else               v = inpW[k * 128 + (j - 1024)];
        nodeW_t[i] = f2bf(v);
        return;
    }
    i -= 147456;
    if (i >= 589824) return;
    int h = i / 147456;
    int r = i % 147456;
    short* img = imgW + h * 147456;
    if (r < 16384) {                        // KW (K=128)
        int colc = r >> 7, k = r & 127;
        img[(colc * 128 + k) ^ ((colc & 7) << 3)] = f2bf(Ke2v[h * 16384 + k * 128 + colc]);
    } else if (r < 32768) {                 // VW (K=128)
        int e = r - 16384; int colc = e >> 7, k = e & 127;
        img[16384 + ((colc * 128 + k) ^ ((colc & 7) << 3))] = f2bf(Ve2v[h * 16384 + k * 128 + colc]);
    } else if (r < 98304) {                 // LU (K=256)
        int e = r - 32768; int c = e >> 14, ec = e & 16383;
        int colc = ec >> 8, k = ec & 255; int col = c * 64 + colc;
        img[32768 + c * 16384 + ((colc * 256 + k) ^ ((colc & 7) << 3))] =
            f2bf(luW[h * 65536 + k * 256 + col]);
    } else if (r < 131072) {                // MSG (K=256)
        int e = r - 98304; int c = e >> 14, ec = e & 16383;
        int colc = ec >> 8, k = ec & 255; int col = c * 64 + colc;
        img[98304 + c * 16384 + ((colc * 256 + k) ^ ((colc & 7) << 3))] =
            f2bf(msgW[h * 32768 + k * 128 + col]);
    } else {                                // CAT (K=128)
        int e = r - 131072; int colc = e >> 7, k = e & 127;
        img[131072 + ((colc * 128 + k) ^ ((colc & 7) << 3))] =
            f2bf(catW[(h * 128 + k) * 128 + colc]);
    }
}

// ---------------- node projections (unchanged, verified) ----------------
__global__ __launch_bounds__(256, 2)
void node_proj(const float* __restrict__ x, const short* __restrict__ nodeW_t,
               short* __restrict__ Kv_all, short* __restrict__ Vv_all,
               float* __restrict__ resid)
{
    __shared__ alignas(16) short xt[64 * 128];
    const int tid = threadIdx.x;
    const int row0 = blockIdx.x * 64;
    #pragma unroll
    for (int it = 0; it < 8; ++it) {
        int idx4 = it * 256 + tid;
        int r = idx4 >> 5;
        int c = (idx4 & 31) * 4;
        float4 v = {0.f, 0.f, 0.f, 0.f};
        if (row0 + r < NN) v = *(const float4*)(x + (size_t)(row0 + r) * 128 + c);
        short4 sw; sw.x = f2bf(v.x); sw.y = f2bf(v.y); sw.z = f2bf(v.z); sw.w = f2bf(v.w);
        int byte = (r * 256 + c * 2) ^ ((r & 7) << 4);
        *(short4*)((char*)xt + byte) = sw;
    }
    __syncthreads();
    const int lane = tid & 63, w = tid >> 6;
    const int l15 = lane & 15, lg = lane >> 4;
    const int rloc = w * 16 + l15;
    s16x8 a[4];
    #pragma unroll
    for (int ks = 0; ks < 4; ++ks) {
        int byte = (rloc * 256 + (ks * 32 + lg * 8) * 2) ^ ((rloc & 7) << 4);
        a[ks] = *(const s16x8*)((const char*)xt + byte);
    }
    const int rowC = row0 + w * 16 + lg * 4;
    for (int nc = 0; nc < 18; ++nc) {
        f32x4 acc[4];
        s16x8 b[16];
        #pragma unroll
        for (int q = 0; q < 4; ++q) {
            acc[q] = (f32x4){0.f, 0.f, 0.f, 0.f};
            int j = (nc * 4 + q) * 16 + l15;
            #pragma unroll
            for (int ks = 0; ks < 4; ++ks)
                b[q * 4 + ks] = *(const s16x8*)(nodeW_t + j * 128 + ks * 32 + lg * 8);
        }
        #pragma unroll
        for (int q = 0; q < 4; ++q)
            #pragma unroll
            for (int ks = 0; ks < 4; ++ks)
                acc[q] = mfma16(a[ks], b[q * 4 + ks], acc[q]);
        #pragma unroll
        for (int q = 0; q < 4; ++q) {
            int j = (nc * 4 + q) * 16 + l15;
            #pragma unroll
            for (int r = 0; r < 4; ++r) {
                int row = rowC + r;
                if (row >= NN) continue;
                if (j < 512)       Kv_all[(size_t)row * 512 + j] = f2bf(acc[q][r]);
                else if (j < 1024) Vv_all[(size_t)row * 512 + (j - 512)] = f2bf(acc[q][r]);
                else               resid[(size_t)row * 128 + (j - 1024)] = acc[q][r];
            }
        }
    }
}

// ---------------- fused edge pipeline: R18 base + native cvt, no setprio ----------------
// Dynamic LDS 100352:
//   wbuf[4] @ 0..32767 (4 x 8KB, rotate chunk%4; 36%4==0 so stable per head)
//   per-wave scratch @32768 + w*12288 (q@0, k1@4096, VE/m2@8192, m1g@0 overlay)
//   bias tables @81920 (floats)
// Per step: [WAITV(4) counted][s_barrier][issue chunk p+3][compute chunk p].
#define B128h(buf, ct, ks) \
    (*(const s16x8*)((const short*)(buf) + (((((ct) * 16 + l15) * 128) + (ks) * 32 + lg * 8) ^ ((l15 & 7) << 3))))
#define B256h(buf, ks) \
    (*(const s16x8*)((const short*)(buf) + ((l15 * 256 + (ks) * 32 + lg * 8) ^ ((l15 & 7) << 3))))
#define WAITV(N) asm volatile("s_waitcnt vmcnt(" #N ")" ::: "memory")
#define SBAR() do { __builtin_amdgcn_s_barrier(); __builtin_amdgcn_sched_barrier(0); } while (0)

__global__ __launch_bounds__(256, 1)
void edge_kernel(const float* __restrict__ ef, const int* __restrict__ eidx,
                 const short* __restrict__ Kv_all, const short* __restrict__ Vv_all,
                 const short* __restrict__ imgW,
                 const float* __restrict__ lu_b, const float* __restrict__ ln1_g,
                 const float* __restrict__ ln1_b, const float* __restrict__ msg_b,
                 const float* __restrict__ ln2_g, const float* __restrict__ ln2_b,
                 float* __restrict__ out1)
{
    extern __shared__ char lds[];
    const int tid = threadIdx.x;
    const int lane = tid & 63, w = tid >> 6;
    const int l15 = lane & 15, lg = lane >> 4;
    const int e0 = blockIdx.x * 64 + w * 16;
    const int rb = lg * 4;
    char* myscr = lds + 32768 + w * 12288;
    float* bls = (float*)(lds + 81920);
    const float scale = 0.0625f;   // 1/sqrt(2*OUT)

    // ---- prologue: bias tables -> LDS ----
    {
        int j = tid;
        #pragma unroll
        for (int it = 0; it < 4; ++it, j += 256) {
            bls[j] = ln1_g[j]; bls[1024 + j] = ln1_b[j]; bls[2048 + j] = lu_b[j];
        }
        bls[3072 + tid] = msg_b[tid];       bls[3072 + 256 + tid] = msg_b[256 + tid];
        bls[3584 + tid] = ln2_g[tid];       bls[3584 + 256 + tid] = ln2_g[256 + tid];
        bls[4096 + tid] = ln2_b[tid];       bls[4096 + 256 + tid] = ln2_b[256 + tid];
        asm volatile("s_waitcnt lgkmcnt(0)" ::: "memory");
    }

    // ef A-fragments; indices
    const float* efr = ef + (size_t)(e0 + l15) * 128 + lg * 8;
    s16x8 aef[4];
    #pragma unroll
    for (int ks = 0; ks < 4; ++ks) {
        float4 v0 = *(const float4*)(efr + ks * 32);
        float4 v1 = *(const float4*)(efr + ks * 32 + 4);
        s16x8 t;
        t[0] = f2bf(v0.x); t[1] = f2bf(v0.y); t[2] = f2bf(v0.z); t[3] = f2bf(v0.w);
        t[4] = f2bf(v1.x); t[5] = f2bf(v1.y); t[6] = f2bf(v1.z); t[7] = f2bf(v1.w);
        aef[ks] = t;
    }
    const int srcA = eidx[e0 + l15];
    int dstC[4];
    #pragma unroll
    for (int r = 0; r < 4; ++r) dstC[r] = eidx[NE + e0 + rb + r];
    const int gRow = lane >> 2;            // 0..15
    const int gChunk = lane & 3;           // 0..3
    const int dstG = eidx[NE + e0 + gRow];
    const int srcG = eidx[e0 + gRow];

    // issue chunks 0,1,2 of head 0
    dma8(imgW,        lds,         w, lane);
    dma8(imgW + 4096, lds + 8192,  w, lane);
    dma8(imgW + 8192, lds + 16384, w, lane);

    f32x4 outc[8];
    #pragma unroll
    for (int nt = 0; nt < 8; ++nt) outc[nt] = (f32x4){0.f, 0.f, 0.f, 0.f};

    for (int h = 0; h < HEADS; ++h) {
        const short* hb = imgW + h * 147456;
        f32x4 accK[8];
        #pragma unroll
        for (int nt = 0; nt < 8; ++nt) accK[nt] = (f32x4){0, 0, 0, 0};
        s16x8 vvr[4];
        unsigned gpk[16][2];

        // ---- p=0..3: KW chunks -> accK ----
        #pragma unroll
        for (int p = 0; p < 4; ++p) {
            WAITV(4); SBAR();
            dma8(hb + (p + 3) * 4096, lds + ((p + 3) & 3) * 8192, w, lane);
            const char* bA = lds + (p & 3) * 8192;
            #pragma unroll
            for (int ks = 0; ks < 4; ++ks) {
                accK[p * 2]     = mfma16(aef[ks], B128h(bA, 0, ks), accK[p * 2]);
                accK[p * 2 + 1] = mfma16(aef[ks], B128h(bA, 1, ks), accK[p * 2 + 1]);
            }
            if (p == 0) {       // q/k1 gather + per-wave scratch write
                #pragma unroll
                for (int j = 0; j < 4; ++j) {
                    s16x8 qv = *(const s16x8*)(Kv_all + (size_t)dstG * 512 + h * 128 + gChunk * 32 + j * 8);
                    s16x8 kv = *(const s16x8*)(Kv_all + (size_t)srcG * 512 + h * 128 + gChunk * 32 + j * 8);
                    int byte = gRow * 256 + ((((gChunk * 4 + j) * 16)) ^ ((gRow & 7) << 4));
                    *(s16x8*)(myscr + byte) = qv;
                    *(s16x8*)(myscr + 4096 + byte) = kv;
                }
            }
        }

        // ---- p=4..7: VW chunks -> VE scratch; p==4: vvr; p==7: LN1+gate ----
        #pragma unroll
        for (int i = 0; i < 4; ++i) {
            const int p = 4 + i;
            WAITV(4); SBAR();
            dma8(hb + (p + 3) * 4096, lds + ((p + 3) & 3) * 8192, w, lane);
            const char* bA = lds + (p & 3) * 8192;
            f32x4 aV0 = (f32x4){0, 0, 0, 0}, aV1 = (f32x4){0, 0, 0, 0};
            #pragma unroll
            for (int ks = 0; ks < 4; ++ks) {
                aV0 = mfma16(aef[ks], B128h(bA, 0, ks), aV0);
                aV1 = mfma16(aef[ks], B128h(bA, 1, ks), aV1);
            }
            #pragma unroll
            for (int t = 0; t < 2; ++t) {
                f32x4 av = t ? aV1 : aV0;
                int c = (i * 2 + t) * 16 + l15;
                #pragma unroll
                for (int r = 0; r < 4; ++r) {
                    int row = rb + r;
                    int byte = 8192 + ((row * 256 + c * 2) ^ ((row & 7) << 4));
                    *(short*)(myscr + byte) = f2bf(av[r]);
                }
            }
            if (i == 0) {
                #pragma unroll
                for (int ks = 0; ks < 4; ++ks)
                    vvr[ks] = *(const s16x8*)(Vv_all + (size_t)srcA * 512 + h * 128 + ks * 32 + lg * 8);
            }
            if (i == 3) {
                #pragma unroll
                for (int r = 0; r < 4; ++r) {       // LN1 + sigmoid gate (verified)
                    const int i2r = rb + r;
                    const int swz = (i2r & 7) << 4;
                    float al[16];
                    float s1 = 0.f, s2 = 0.f;
                    #pragma unroll
                    for (int nt = 0; nt < 8; ++nt) {
                        int off = (i2r * 256 + nt * 32 + l15 * 2) ^ swz;
                        float q  = bf2f(*(const short*)(myscr + off));
                        float k1 = bf2f(*(const short*)(myscr + 4096 + off));
                        float alo = q * k1 * scale;
                        float ahi = q * accK[nt][r] * scale;
                        al[nt] = alo; al[nt + 8] = ahi;
                        s1 += alo + ahi; s2 += alo * alo + ahi * ahi;
                    }
                    #pragma unroll
                    for (int m = 1; m < 16; m <<= 1) { s1 += __shfl_xor(s1, m); s2 += __shfl_xor(s2, m); }
                    float mean = s1 * (1.f / 256.f);
                    float var  = s2 * (1.f / 256.f) - mean * mean;
                    float rstd = rsqrtf(var + EPSV);
                    #pragma unroll
                    for (int i2 = 0; i2 < 16; ++i2) {
                        int c = i2 * 16 + l15;
                        float z = (al[i2] - mean) * rstd * bls[h * 256 + c] + bls[1024 + h * 256 + c];
                        float g = 1.f / (1.f + __expf(-z));
                        unsigned gb = (unsigned)(unsigned short)f2bf(g);
                        if ((r & 1) == 0) gpk[i2][r >> 1] = gb;
                        else              gpk[i2][r >> 1] |= gb << 16;
                    }
                }
            }
        }

        // ---- p=8..23: LU chunks, one m1 tile per step (dual 4-deep chains) ----
        #pragma unroll
        for (int c = 0; c < 16; ++c) {
            const int p = 8 + c;
            WAITV(4); SBAR();
            dma8(hb + (p + 3) * 4096, lds + ((p + 3) & 3) * 8192, w, lane);
            const char* bA = lds + (p & 3) * 8192;
            f32x4 m1a = (f32x4){0, 0, 0, 0}, m1b = (f32x4){0, 0, 0, 0};
            #pragma unroll
            for (int ks = 0; ks < 4; ++ks) {
                m1a = mfma16(vvr[ks], B256h(bA, ks), m1a);
                int byte = 8192 + ((l15 * 256 + (ks * 32 + lg * 8) * 2) ^ ((l15 & 7) << 4));
                s16x8 a = *(const s16x8*)(myscr + byte);
                m1b = mfma16(a, B256h(bA, ks + 4), m1b);
            }
            {
                int col = c * 16 + l15;
                float bias = bls[2048 + h * 256 + col];
                #pragma unroll
                for (int r = 0; r < 4; ++r) {
                    float g = bf2f((short)((gpk[c][r >> 1] >> ((r & 1) * 16)) & 0xFFFFu));
                    int row = rb + r;
                    int byte = (row * 512 + col * 2) ^ ((row & 7) << 4);
                    *(short*)(myscr + byte) = f2bf((m1a[r] + m1b[r] + bias) * g);
                }
            }
        }

        // ---- p=24..31: MSG chunks -> m2 regs (dual 4-deep chains) ----
        f32x4 m2[8];
        #pragma unroll
        for (int nt = 0; nt < 8; ++nt) m2[nt] = (f32x4){0, 0, 0, 0};
        #pragma unroll
        for (int c = 0; c < 8; ++c) {
            const int p = 24 + c;
            WAITV(4); SBAR();
            dma8(hb + (p + 3) * 4096, lds + ((p + 3) & 3) * 8192, w, lane);
            const char* bA = lds + (p & 3) * 8192;
            f32x4 mba = (f32x4){0, 0, 0, 0}, mbb = (f32x4){0, 0, 0, 0};
            #pragma unroll
            for (int ks = 0; ks < 4; ++ks) {
                int byteA = (l15 * 512 + (ks * 32 + lg * 8) * 2) ^ ((l15 & 7) << 4);
                s16x8 aA = *(const s16x8*)(myscr + byteA);
                mba = mfma16(aA, B256h(bA, ks), mba);
                int byteB = (l15 * 512 + ((ks + 4) * 32 + lg * 8) * 2) ^ ((l15 & 7) << 4);
                s16x8 aB = *(const s16x8*)(myscr + byteB);
                mbb = mfma16(aB, B256h(bA, ks + 4), mbb);
            }
            #pragma unroll
            for (int r = 0; r < 4; ++r) m2[c][r] = mba[r] + mbb[r];
        }
        {   // LN2 + leaky -> m2 scratch @8192 (verified)
            float s1[4] = {0, 0, 0, 0}, s2[4] = {0, 0, 0, 0};
            #pragma unroll
            for (int nt = 0; nt < 8; ++nt) {
                int c = nt * 16 + l15;
                float bias = bls[3072 + h * 128 + c];
                #pragma unroll
                for (int r = 0; r < 4; ++r) {
                    float v = m2[nt][r] + bias;
                    m2[nt][r] = v;
                    s1[r] += v; s2[r] += v * v;
                }
            }
            #pragma unroll
            for (int m = 1; m < 16; m <<= 1)
                #pragma unroll
                for (int r = 0; r < 4; ++r) { s1[r] += __shfl_xor(s1[r], m); s2[r] += __shfl_xor(s2[r], m); }
            float mean[4], rstd[4];
            #pragma unroll
            for (int r = 0; r < 4; ++r) {
                mean[r] = s1[r] * (1.f / 128.f);
                float var = s2[r] * (1.f / 128.f) - mean[r] * mean[r];
                rstd[r] = rsqrtf(var + EPSV);
            }
            #pragma unroll
            for (int nt = 0; nt < 8; ++nt) {
                int c = nt * 16 + l15;
                float g2 = bls[3584 + h * 128 + c], b2 = bls[4096 + h * 128 + c];
                #pragma unroll
                for (int r = 0; r < 4; ++r) {
                    float v = (m2[nt][r] - mean[r]) * rstd[r] * g2 + b2;
                    v = v > 0.f ? v : v * NEGS;
                    int row = rb + r;
                    int byte = 8192 + ((row * 256 + c * 2) ^ ((row & 7) << 4));
                    *(short*)(myscr + byte) = f2bf(v);
                }
            }
        }

        // ---- p=32..35: CAT chunks -> outc; prefetch crosses into next head ----
        #pragma unroll
        for (int c = 0; c < 4; ++c) {
            const int p = 32 + c;
            if (p < 34)      { WAITV(4); }
            else if (p == 34) { if (h < 3) { WAITV(4); } else { WAITV(2); } }
            else              { if (h < 3) { WAITV(4); } else { WAITV(0); } }
            SBAR();
            const int t = p + 3;            // 35,36,37,38
            if (t < 36) {
                dma8(hb + t * 4096, lds + (t & 3) * 8192, w, lane);
            } else if (h < 3) {
                dma8(imgW + (h + 1) * 147456 + (t - 36) * 4096, lds + (t & 3) * 8192, w, lane);
            }
            const char* bA = lds + (p & 3) * 8192;
            #pragma unroll
            for (int ks = 0; ks < 4; ++ks) {
                int byte = 8192 + ((l15 * 256 + (ks * 32 + lg * 8) * 2) ^ ((l15 & 7) << 4));
                s16x8 a = *(const s16x8*)(myscr + byte);
                outc[c * 2]     = mfma16(a, B128h(bA, 0, ks), outc[c * 2]);
                outc[c * 2 + 1] = mfma16(a, B128h(bA, 1, ks), outc[c * 2 + 1]);
            }
        }
    }

    // ---- scatter: one 128-wide atomic add per edge ----
    #pragma unroll
    for (int nt = 0; nt < 8; ++nt) {
        int c = nt * 16 + l15;
        #pragma unroll
        for (int r = 0; r < 4; ++r)
            atomicAdd(out1 + (size_t)dstC[r] * 128 + c, outc[nt][r]);
    }
}

// ---------------- BN statistics ----------------
__global__ void bn_stats(const float* __restrict__ out1, const float* __restrict__ cat_b,
                         float* __restrict__ stats)
{
    const int col = threadIdx.x;
    const int r0 = blockIdx.x * 128;
    const float cb = cat_b[col];
    float s = 0.f, s2 = 0.f;
    for (int i = 0; i < 128; ++i) {
        int row = r0 + i;
        if (row < NN) {
            float v = out1[(size_t)row * 128 + col] + cb;
            s += v; s2 += v * v;
        }
    }
    atomicAdd(stats + col, s);
    atomicAdd(stats + 128 + col, s2);
}

// ---------------- finalize: BN + leaky + residual ----------------
__global__ void finalize(const float* __restrict__ out1, const float* __restrict__ resid,
                         const float* __restrict__ stats, const float* __restrict__ cat_b,
                         const float* __restrict__ bn_g, const float* __restrict__ bn_b,
                         const float* __restrict__ inp_b, float* __restrict__ out)
{
    int i = blockIdx.x * 256 + threadIdx.x;
    if (i >= NN * 128) return;
    int col = i & 127;
    float mu = stats[col] * (1.f / NN);
    float var = stats[128 + col] * (1.f / NN) - mu * mu;
    float rstd = rsqrtf(var + EPSV);
    float v = out1[i] + cat_b[col];
    v = (v - mu) * rstd * bn_g[col] + bn_b[col];
    v = v > 0.f ? v : v * NEGS;
    out[i] = v + resid[i] + inp_b[col];
}

extern "C" void kernel_launch(void* const* d_in, const int* in_sizes, int n_in,
                              void* d_out, int out_size, void* d_ws, size_t ws_size,
                              hipStream_t stream)
{
    (void)in_sizes; (void)n_in; (void)out_size; (void)ws_size;
    const float* x     = (const float*)d_in[0];
    const int*   eidx  = (const int*)d_in[1];
    const float* ef    = (const float*)d_in[2];
    const float* Kv2v  = (const float*)d_in[3];
    const float* Ke2v  = (const float*)d_in[4];
    const float* Vv2v  = (const float*)d_in[5];
    const float* Ve2v  = (const float*)d_in[6];
    const float* lu_W  = (const float*)d_in[7];
    const float* lu_b  = (const float*)d_in[8];
    const float* ln1_g = (const float*)d_in[9];
    const float* ln1_b = (const float*)d_in[10];
    const float* msg_W = (const float*)d_in[11];
    const float* msg_b = (const float*)d_in[12];
    const float* ln2_g = (const float*)d_in[13];
    const float* ln2_b = (const float*)d_in[14];
    const float* cat_W = (const float*)d_in[15];
    const float* cat_b = (const float*)d_in[16];
    const float* inp_W = (const float*)d_in[17];
    const float* inp_b = (const float*)d_in[18];
    const float* bn_g  = (const float*)d_in[19];
    const float* bn_b  = (const float*)d_in[20];

    char* ws = (char*)d_ws;
    short* nodeW_t = (short*)(ws + 0);          // 294912
    short* imgW    = (short*)(ws + 294912);     // 1179648 (4 heads x 294912)
    short* Kv_all  = (short*)(ws + 1474560);    // 51,200,000
    short* Vv_all  = (short*)(ws + 52674560);   // 51,200,000
    float* resid   = (float*)(ws + 103874560);  // 25,600,000
    float* out1    = (float*)(ws + 129474560);  // 25,600,000
    float* stats   = (float*)(ws + 155074560);  // 1024

    hipFuncSetAttribute((const void*)edge_kernel,
                        hipFuncAttributeMaxDynamicSharedMemorySize, 100352);

    hipMemsetAsync(out1, 0, 25600000 + 1024, stream);   // out1 + stats (contiguous)
    prep_weights<<<2880, 256, 0, stream>>>(Kv2v, Vv2v, inp_W, Ke2v, Ve2v, lu_W, msg_W, cat_W,
                                           nodeW_t, imgW);
    node_proj<<<782, 256, 0, stream>>>(x, nodeW_t, Kv_all, Vv_all, resid);
    edge_kernel<<<3125, 256, 100352, stream>>>(ef, eidx, Kv_all, Vv_all, imgW,
                                               lu_b, ln1_g, ln1_b, msg_b,
                                               ln2_g, ln2_b, out1);
    bn_stats<<<391, 128, 0, stream>>>(out1, cat_b, stats);
    finalize<<<25000, 256, 0, stream>>>(out1, resid, stats, cat_b, bn_g, bn_b, inp_b,
                                        (float*)d_out);
}

// Round 22
// 1307.571 us; speedup vs baseline: 1.0939x; 1.0026x over previous
//
#include <hip/hip_runtime.h>
#include <hip/hip_bf16.h>

#define NN 50000
#define NE 200000
#define HEADS 4
#define EPSV 1e-5f
#define NEGS 0.01f

using f32x4 = __attribute__((ext_vector_type(4))) float;
using s16x8 = __attribute__((ext_vector_type(8))) short;
using bf16x8 = __attribute__((ext_vector_type(8))) __bf16;

// native bf16 convert: compiles to the hw cvt op (RNE), ~1 VALU vs ~5 for the
// hand-rolled union version (guide m240: scalar cast is the fast path)
__device__ __forceinline__ short f2bf(float f) {
    __bf16 b = (__bf16)f;
    return __builtin_bit_cast(short, b);
}
__device__ __forceinline__ float bf2f(short s) {
    union { unsigned u; float f; } v; v.u = ((unsigned)(unsigned short)s) << 16;
    return v.f;
}
__device__ __forceinline__ f32x4 mfma16(s16x8 a, s16x8 b, f32x4 c) {
    return __builtin_amdgcn_mfma_f32_16x16x32_bf16(
        __builtin_bit_cast(bf16x8, a), __builtin_bit_cast(bf16x8, b), c, 0, 0, 0);
}
__device__ __forceinline__ void gld16(const void* g, void* l) {
    __builtin_amdgcn_global_load_lds(
        (const __attribute__((address_space(1))) void*)g,
        (__attribute__((address_space(3))) void*)l, 16, 0, 0);
}
// DMA one 8KB chunk (4096 shorts) image -> LDS, 256 threads, 2 ops each
__device__ __forceinline__ void dma8(const short* src, char* dst, int w, int lane) {
    gld16(src + w * 512 + lane * 8,        dst + w * 1024);
    gld16(src + 2048 + w * 512 + lane * 8, dst + 4096 + w * 1024);
}

// ---------------- weight prep (unchanged, verified) ----------------
// imgW per-head = 36 contiguous 4096-short (8KB) chunks:
//   KW: 0-3, VW: 4-7, LU: 8-23, MSG: 24-31, CAT: 32-35.
__global__ void prep_weights(const float* __restrict__ Kv2v, const float* __restrict__ Vv2v,
                             const float* __restrict__ inpW,
                             const float* __restrict__ Ke2v, const float* __restrict__ Ve2v,
                             const float* __restrict__ luW, const float* __restrict__ msgW,
                             const float* __restrict__ catW,
                             short* __restrict__ nodeW_t, short* __restrict__ imgW)
{
    int i = blockIdx.x * 256 + threadIdx.x;
    if (i < 147456) {                       // nodeW_t [1152][128]
        int j = i >> 7, k = i & 127;
        float v;
        if (j < 512)       v = Kv2v[(j >> 7) * 16384 + k * 128 + (j & 127)];
        else if (j < 1024) v = Vv2v[((j - 512) >> 7) * 16384 + k * 128 + (j & 127)];
        else               v = inpW[k * 128 + (j - 1024)];
        nodeW_t[i] = f2bf(v);
        return;
    }
    i -= 147456;
    if (i >= 589824) return;
    int h = i / 147456;
    int r = i % 147456;
    short* img = imgW + h * 147456;
    if (r < 16384) {                        // KW (K=128)
        int colc = r >> 7, k = r & 127;
        img[(colc * 128 + k) ^ ((colc & 7) << 3)] = f2bf(Ke2v[h * 16384 + k * 128 + colc]);
    } else if (r < 32768) {                 // VW (K=128)
        int e = r - 16384; int colc = e >> 7, k = e & 127;
        img[16384 + ((colc * 128 + k) ^ ((colc & 7) << 3))] = f2bf(Ve2v[h * 16384 + k * 128 + colc]);
    } else if (r < 98304) {                 // LU (K=256)
        int e = r - 32768; int c = e >> 14, ec = e & 16383;
        int colc = ec >> 8, k = ec & 255; int col = c * 64 + colc;
        img[32768 + c * 16384 + ((colc * 256 + k) ^ ((colc & 7) << 3))] =
            f2bf(luW[h * 65536 + k * 256 + col]);
    } else if (r < 131072) {                // MSG (K=256)
        int e = r - 98304; int c = e >> 14, ec = e & 16383;
        int colc = ec >> 8, k = ec & 255; int col = c * 64 + colc;
        img[98304 + c * 16384 + ((colc * 256 + k) ^ ((colc & 7) << 3))] =
            f2bf(msgW[h * 32768 + k * 128 + col]);
    } else {                                // CAT (K=128)
        int e = r - 131072; int colc = e >> 7, k = e & 127;
        img[131072 + ((colc * 128 + k) ^ ((colc & 7) << 3))] =
            f2bf(catW[(h * 128 + k) * 128 + colc]);
    }
}

// ---------------- node projections (unchanged, verified) ----------------
__global__ __launch_bounds__(256, 2)
void node_proj(const float* __restrict__ x, const short* __restrict__ nodeW_t,
               short* __restrict__ Kv_all, short* __restrict__ Vv_all,
               float* __restrict__ resid)
{
    __shared__ alignas(16) short xt[64 * 128];
    const int tid = threadIdx.x;
    const int row0 = blockIdx.x * 64;
    #pragma unroll
    for (int it = 0; it < 8; ++it) {
        int idx4 = it * 256 + tid;
        int r = idx4 >> 5;
        int c = (idx4 & 31) * 4;
        float4 v = {0.f, 0.f, 0.f, 0.f};
        if (row0 + r < NN) v = *(const float4*)(x + (size_t)(row0 + r) * 128 + c);
        short4 sw; sw.x = f2bf(v.x); sw.y = f2bf(v.y); sw.z = f2bf(v.z); sw.w = f2bf(v.w);
        int byte = (r * 256 + c * 2) ^ ((r & 7) << 4);
        *(short4*)((char*)xt + byte) = sw;
    }
    __syncthreads();
    const int lane = tid & 63, w = tid >> 6;
    const int l15 = lane & 15, lg = lane >> 4;
    const int rloc = w * 16 + l15;
    s16x8 a[4];
    #pragma unroll
    for (int ks = 0; ks < 4; ++ks) {
        int byte = (rloc * 256 + (ks * 32 + lg * 8) * 2) ^ ((rloc & 7) << 4);
        a[ks] = *(const s16x8*)((const char*)xt + byte);
    }
    const int rowC = row0 + w * 16 + lg * 4;
    for (int nc = 0; nc < 18; ++nc) {
        f32x4 acc[4];
        s16x8 b[16];
        #pragma unroll
        for (int q = 0; q < 4; ++q) {
            acc[q] = (f32x4){0.f, 0.f, 0.f, 0.f};
            int j = (nc * 4 + q) * 16 + l15;
            #pragma unroll
            for (int ks = 0; ks < 4; ++ks)
                b[q * 4 + ks] = *(const s16x8*)(nodeW_t + j * 128 + ks * 32 + lg * 8);
        }
        #pragma unroll
        for (int q = 0; q < 4; ++q)
            #pragma unroll
            for (int ks = 0; ks < 4; ++ks)
                acc[q] = mfma16(a[ks], b[q * 4 + ks], acc[q]);
        #pragma unroll
        for (int q = 0; q < 4; ++q) {
            int j = (nc * 4 + q) * 16 + l15;
            #pragma unroll
            for (int r = 0; r < 4; ++r) {
                int row = rowC + r;
                if (row >= NN) continue;
                if (j < 512)       Kv_all[(size_t)row * 512 + j] = f2bf(acc[q][r]);
                else if (j < 1024) Vv_all[(size_t)row * 512 + (j - 512)] = f2bf(acc[q][r]);
                else               resid[(size_t)row * 128 + (j - 1024)] = acc[q][r];
            }
        }
    }
}

// ---------------- fused edge pipeline: verified best (R19) ----------------
// Dynamic LDS 100352:
//   wbuf[4] @ 0..32767 (4 x 8KB, rotate chunk%4; 36%4==0 so stable per head)
//   per-wave scratch @32768 + w*12288 (q@0, k1@4096, VE/m2@8192, m1g@0 overlay)
//   bias tables @81920 (floats)
// Per step: [WAITV(4) counted][s_barrier][issue chunk p+3][compute chunk p].
#define B128h(buf, ct, ks) \
    (*(const s16x8*)((const short*)(buf) + (((((ct) * 16 + l15) * 128) + (ks) * 32 + lg * 8) ^ ((l15 & 7) << 3))))
#define B256h(buf, ks) \
    (*(const s16x8*)((const short*)(buf) + ((l15 * 256 + (ks) * 32 + lg * 8) ^ ((l15 & 7) << 3))))
#define WAITV(N) asm volatile("s_waitcnt vmcnt(" #N ")" ::: "memory")
#define SBAR() do { __builtin_amdgcn_s_barrier(); __builtin_amdgcn_sched_barrier(0); } while (0)

__global__ __launch_bounds__(256, 1)
void edge_kernel(const float* __restrict__ ef, const int* __restrict__ eidx,
                 const short* __restrict__ Kv_all, const short* __restrict__ Vv_all,
                 const short* __restrict__ imgW,
                 const float* __restrict__ lu_b, const float* __restrict__ ln1_g,
                 const float* __restrict__ ln1_b, const float* __restrict__ msg_b,
                 const float* __restrict__ ln2_g, const float* __restrict__ ln2_b,
                 float* __restrict__ out1)
{
    extern __shared__ char lds[];
    const int tid = threadIdx.x;
    const int lane = tid & 63, w = tid >> 6;
    const int l15 = lane & 15, lg = lane >> 4;
    const int e0 = blockIdx.x * 64 + w * 16;
    const int rb = lg * 4;
    char* myscr = lds + 32768 + w * 12288;
    float* bls = (float*)(lds + 81920);
    const float scale = 0.0625f;   // 1/sqrt(2*OUT)

    // ---- prologue: bias tables -> LDS ----
    {
        int j = tid;
        #pragma unroll
        for (int it = 0; it < 4; ++it, j += 256) {
            bls[j] = ln1_g[j]; bls[1024 + j] = ln1_b[j]; bls[2048 + j] = lu_b[j];
        }
        bls[3072 + tid] = msg_b[tid];       bls[3072 + 256 + tid] = msg_b[256 + tid];
        bls[3584 + tid] = ln2_g[tid];       bls[3584 + 256 + tid] = ln2_g[256 + tid];
        bls[4096 + tid] = ln2_b[tid];       bls[4096 + 256 + tid] = ln2_b[256 + tid];
        asm volatile("s_waitcnt lgkmcnt(0)" ::: "memory");
    }

    // ef A-fragments; indices
    const float* efr = ef + (size_t)(e0 + l15) * 128 + lg * 8;
    s16x8 aef[4];
    #pragma unroll
    for (int ks = 0; ks < 4; ++ks) {
        float4 v0 = *(const float4*)(efr + ks * 32);
        float4 v1 = *(const float4*)(efr + ks * 32 + 4);
        s16x8 t;
        t[0] = f2bf(v0.x); t[1] = f2bf(v0.y); t[2] = f2bf(v0.z); t[3] = f2bf(v0.w);
        t[4] = f2bf(v1.x); t[5] = f2bf(v1.y); t[6] = f2bf(v1.z); t[7] = f2bf(v1.w);
        aef[ks] = t;
    }
    const int srcA = eidx[e0 + l15];
    int dstC[4];
    #pragma unroll
    for (int r = 0; r < 4; ++r) dstC[r] = eidx[NE + e0 + rb + r];
    const int gRow = lane >> 2;            // 0..15
    const int gChunk = lane & 3;           // 0..3
    const int dstG = eidx[NE + e0 + gRow];
    const int srcG = eidx[e0 + gRow];

    // issue chunks 0,1,2 of head 0
    dma8(imgW,        lds,         w, lane);
    dma8(imgW + 4096, lds + 8192,  w, lane);
    dma8(imgW + 8192, lds + 16384, w, lane);

    f32x4 outc[8];
    #pragma unroll
    for (int nt = 0; nt < 8; ++nt) outc[nt] = (f32x4){0.f, 0.f, 0.f, 0.f};

    for (int h = 0; h < HEADS; ++h) {
        const short* hb = imgW + h * 147456;
        f32x4 accK[8];
        #pragma unroll
        for (int nt = 0; nt < 8; ++nt) accK[nt] = (f32x4){0, 0, 0, 0};
        s16x8 vvr[4];
        unsigned gpk[16][2];

        // ---- p=0..3: KW chunks -> accK ----
        #pragma unroll
        for (int p = 0; p < 4; ++p) {
            WAITV(4); SBAR();
            dma8(hb + (p + 3) * 4096, lds + ((p + 3) & 3) * 8192, w, lane);
            const char* bA = lds + (p & 3) * 8192;
            #pragma unroll
            for (int ks = 0; ks < 4; ++ks) {
                accK[p * 2]     = mfma16(aef[ks], B128h(bA, 0, ks), accK[p * 2]);
                accK[p * 2 + 1] = mfma16(aef[ks], B128h(bA, 1, ks), accK[p * 2 + 1]);
            }
            if (p == 0) {       // q/k1 gather + per-wave scratch write
                #pragma unroll
                for (int j = 0; j < 4; ++j) {
                    s16x8 qv = *(const s16x8*)(Kv_all + (size_t)dstG * 512 + h * 128 + gChunk * 32 + j * 8);
                    s16x8 kv = *(const s16x8*)(Kv_all + (size_t)srcG * 512 + h * 128 + gChunk * 32 + j * 8);
                    int byte = gRow * 256 + ((((gChunk * 4 + j) * 16)) ^ ((gRow & 7) << 4));
                    *(s16x8*)(myscr + byte) = qv;
                    *(s16x8*)(myscr + 4096 + byte) = kv;
                }
            }
        }

        // ---- p=4..7: VW chunks -> VE scratch; p==4: vvr; p==7: LN1+gate ----
        #pragma unroll
        for (int i = 0; i < 4; ++i) {
            const int p = 4 + i;
            WAITV(4); SBAR();
            dma8(hb + (p + 3) * 4096, lds + ((p + 3) & 3) * 8192, w, lane);
            const char* bA = lds + (p & 3) * 8192;
            f32x4 aV0 = (f32x4){0, 0, 0, 0}, aV1 = (f32x4){0, 0, 0, 0};
            #pragma unroll
            for (int ks = 0; ks < 4; ++ks) {
                aV0 = mfma16(aef[ks], B128h(bA, 0, ks), aV0);
                aV1 = mfma16(aef[ks], B128h(bA, 1, ks), aV1);
            }
            #pragma unroll
            for (int t = 0; t < 2; ++t) {
                f32x4 av = t ? aV1 : aV0;
                int c = (i * 2 + t) * 16 + l15;
                #pragma unroll
                for (int r = 0; r < 4; ++r) {
                    int row = rb + r;
                    int byte = 8192 + ((row * 256 + c * 2) ^ ((row & 7) << 4));
                    *(short*)(myscr + byte) = f2bf(av[r]);
                }
            }
            if (i == 0) {
                #pragma unroll
                for (int ks = 0; ks < 4; ++ks)
                    vvr[ks] = *(const s16x8*)(Vv_all + (size_t)srcA * 512 + h * 128 + ks * 32 + lg * 8);
            }
            if (i == 3) {
                #pragma unroll
                for (int r = 0; r < 4; ++r) {       // LN1 + sigmoid gate (verified)
                    const int i2r = rb + r;
                    const int swz = (i2r & 7) << 4;
                    float al[16];
                    float s1 = 0.f, s2 = 0.f;
                    #pragma unroll
                    for (int nt = 0; nt < 8; ++nt) {
                        int off = (i2r * 256 + nt * 32 + l15 * 2) ^ swz;
                        float q  = bf2f(*(const short*)(myscr + off));
                        float k1 = bf2f(*(const short*)(myscr + 4096 + off));
                        float alo = q * k1 * scale;
                        float ahi = q * accK[nt][r] * scale;
                        al[nt] = alo; al[nt + 8] = ahi;
                        s1 += alo + ahi; s2 += alo * alo + ahi * ahi;
                    }
                    #pragma unroll
                    for (int m = 1; m < 16; m <<= 1) { s1 += __shfl_xor(s1, m); s2 += __shfl_xor(s2, m); }
                    float mean = s1 * (1.f / 256.f);
                    float var  = s2 * (1.f / 256.f) - mean * mean;
                    float rstd = rsqrtf(var + EPSV);
                    #pragma unroll
                    for (int i2 = 0; i2 < 16; ++i2) {
                        int c = i2 * 16 + l15;
                        float z = (al[i2] - mean) * rstd * bls[h * 256 + c] + bls[1024 + h * 256 + c];
                        float g = 1.f / (1.f + __expf(-z));
                        unsigned gb = (unsigned)(unsigned short)f2bf(g);
                        if ((r & 1) == 0) gpk[i2][r >> 1] = gb;
                        else              gpk[i2][r >> 1] |= gb << 16;
                    }
                }
            }
        }

        // ---- p=8..23: LU chunks, one m1 tile per step (dual 4-deep chains) ----
        #pragma unroll
        for (int c = 0; c < 16; ++c) {
            const int p = 8 + c;
            WAITV(4); SBAR();
            dma8(hb + (p + 3) * 4096, lds + ((p + 3) & 3) * 8192, w, lane);
            const char* bA = lds + (p & 3) * 8192;
            f32x4 m1a = (f32x4){0, 0, 0, 0}, m1b = (f32x4){0, 0, 0, 0};
            #pragma unroll
            for (int ks = 0; ks < 4; ++ks) {
                m1a = mfma16(vvr[ks], B256h(bA, ks), m1a);
                int byte = 8192 + ((l15 * 256 + (ks * 32 + lg * 8) * 2) ^ ((l15 & 7) << 4));
                s16x8 a = *(const s16x8*)(myscr + byte);
                m1b = mfma16(a, B256h(bA, ks + 4), m1b);
            }
            {
                int col = c * 16 + l15;
                float bias = bls[2048 + h * 256 + col];
                #pragma unroll
                for (int r = 0; r < 4; ++r) {
                    float g = bf2f((short)((gpk[c][r >> 1] >> ((r & 1) * 16)) & 0xFFFFu));
                    int row = rb + r;
                    int byte = (row * 512 + col * 2) ^ ((row & 7) << 4);
                    *(short*)(myscr + byte) = f2bf((m1a[r] + m1b[r] + bias) * g);
                }
            }
        }

        // ---- p=24..31: MSG chunks -> m2 regs (dual 4-deep chains) ----
        f32x4 m2[8];
        #pragma unroll
        for (int nt = 0; nt < 8; ++nt) m2[nt] = (f32x4){0, 0, 0, 0};
        #pragma unroll
        for (int c = 0; c < 8; ++c) {
            const int p = 24 + c;
            WAITV(4); SBAR();
            dma8(hb + (p + 3) * 4096, lds + ((p + 3) & 3) * 8192, w, lane);
            const char* bA = lds + (p & 3) * 8192;
            f32x4 mba = (f32x4){0, 0, 0, 0}, mbb = (f32x4){0, 0, 0, 0};
            #pragma unroll
            for (int ks = 0; ks < 4; ++ks) {
                int byteA = (l15 * 512 + (ks * 32 + lg * 8) * 2) ^ ((l15 & 7) << 4);
                s16x8 aA = *(const s16x8*)(myscr + byteA);
                mba = mfma16(aA, B256h(bA, ks), mba);
                int byteB = (l15 * 512 + ((ks + 4) * 32 + lg * 8) * 2) ^ ((l15 & 7) << 4);
                s16x8 aB = *(const s16x8*)(myscr + byteB);
                mbb = mfma16(aB, B256h(bA, ks + 4), mbb);
            }
            #pragma unroll
            for (int r = 0; r < 4; ++r) m2[c][r] = mba[r] + mbb[r];
        }
        {   // LN2 + leaky -> m2 scratch @8192 (verified)
            float s1[4] = {0, 0, 0, 0}, s2[4] = {0, 0, 0, 0};
            #pragma unroll
            for (int nt = 0; nt < 8; ++nt) {
                int c = nt * 16 + l15;
                float bias = bls[3072 + h * 128 + c];
                #pragma unroll
                for (int r = 0; r < 4; ++r) {
                    float v = m2[nt][r] + bias;
                    m2[nt][r] = v;
                    s1[r] += v; s2[r] += v * v;
                }
            }
            #pragma unroll
            for (int m = 1; m < 16; m <<= 1)
                #pragma unroll
                for (int r = 0; r < 4; ++r) { s1[r] += __shfl_xor(s1[r], m); s2[r] += __shfl_xor(s2[r], m); }
            float mean[4], rstd[4];
            #pragma unroll
            for (int r = 0; r < 4; ++r) {
                mean[r] = s1[r] * (1.f / 128.f);
                float var = s2[r] * (1.f / 128.f) - mean[r] * mean[r];
                rstd[r] = rsqrtf(var + EPSV);
            }
            #pragma unroll
            for (int nt = 0; nt < 8; ++nt) {
                int c = nt * 16 + l15;
                float g2 = bls[3584 + h * 128 + c], b2 = bls[4096 + h * 128 + c];
                #pragma unroll
                for (int r = 0; r < 4; ++r) {
                    float v = (m2[nt][r] - mean[r]) * rstd[r] * g2 + b2;
                    v = v > 0.f ? v : v * NEGS;
                    int row = rb + r;
                    int byte = 8192 + ((row * 256 + c * 2) ^ ((row & 7) << 4));
                    *(short*)(myscr + byte) = f2bf(v);
                }
            }
        }

        // ---- p=32..35: CAT chunks -> outc; prefetch crosses into next head ----
        #pragma unroll
        for (int c = 0; c < 4; ++c) {
            const int p = 32 + c;
            if (p < 34)      { WAITV(4); }
            else if (p == 34) { if (h < 3) { WAITV(4); } else { WAITV(2); } }
            else              { if (h < 3) { WAITV(4); } else { WAITV(0); } }
            SBAR();
            const int t = p + 3;            // 35,36,37,38
            if (t < 36) {
                dma8(hb + t * 4096, lds + (t & 3) * 8192, w, lane);
            } else if (h < 3) {
                dma8(imgW + (h + 1) * 147456 + (t - 36) * 4096, lds + (t & 3) * 8192, w, lane);
            }
            const char* bA = lds + (p & 3) * 8192;
            #pragma unroll
            for (int ks = 0; ks < 4; ++ks) {
                int byte = 8192 + ((l15 * 256 + (ks * 32 + lg * 8) * 2) ^ ((l15 & 7) << 4));
                s16x8 a = *(const s16x8*)(myscr + byte);
                outc[c * 2]     = mfma16(a, B128h(bA, 0, ks), outc[c * 2]);
                outc[c * 2 + 1] = mfma16(a, B128h(bA, 1, ks), outc[c * 2 + 1]);
            }
        }
    }

    // ---- scatter: one 128-wide atomic add per edge ----
    #pragma unroll
    for (int nt = 0; nt < 8; ++nt) {
        int c = nt * 16 + l15;
        #pragma unroll
        for (int r = 0; r < 4; ++r)
            atomicAdd(out1 + (size_t)dstC[r] * 128 + c, outc[nt][r]);
    }
}

// ---------------- BN statistics ----------------
__global__ void bn_stats(const float* __restrict__ out1, const float* __restrict__ cat_b,
                         float* __restrict__ stats)
{
    const int col = threadIdx.x;
    const int r0 = blockIdx.x * 128;
    const float cb = cat_b[col];
    float s = 0.f, s2 = 0.f;
    for (int i = 0; i < 128; ++i) {
        int row = r0 + i;
        if (row < NN) {
            float v = out1[(size_t)row * 128 + col] + cb;
            s += v; s2 += v * v;
        }
    }
    atomicAdd(stats + col, s);
    atomicAdd(stats + 128 + col, s2);
}

// ---------------- finalize: BN + leaky + residual ----------------
__global__ void finalize(const float* __restrict__ out1, const float* __restrict__ resid,
                         const float* __restrict__ stats, const float* __restrict__ cat_b,
                         const float* __restrict__ bn_g, const float* __restrict__ bn_b,
                         const float* __restrict__ inp_b, float* __restrict__ out)
{
    int i = blockIdx.x * 256 + threadIdx.x;
    if (i >= NN * 128) return;
    int col = i & 127;
    float mu = stats[col] * (1.f / NN);
    float var = stats[128 + col] * (1.f / NN) - mu * mu;
    float rstd = rsqrtf(var + EPSV);
    float v = out1[i] + cat_b[col];
    v = (v - mu) * rstd * bn_g[col] + bn_b[col];
    v = v > 0.f ? v : v * NEGS;
    out[i] = v + resid[i] + inp_b[col];
}

extern "C" void kernel_launch(void* const* d_in, const int* in_sizes, int n_in,
                              void* d_out, int out_size, void* d_ws, size_t ws_size,
                              hipStream_t stream)
{
    (void)in_sizes; (void)n_in; (void)out_size; (void)ws_size;
    const float* x     = (const float*)d_in[0];
    const int*   eidx  = (const int*)d_in[1];
    const float* ef    = (const float*)d_in[2];
    const float* Kv2v  = (const float*)d_in[3];
    const float* Ke2v  = (const float*)d_in[4];
    const float* Vv2v  = (const float*)d_in[5];
    const float* Ve2v  = (const float*)d_in[6];
    const float* lu_W  = (const float*)d_in[7];
    const float* lu_b  = (const float*)d_in[8];
    const float* ln1_g = (const float*)d_in[9];
    const float* ln1_b = (const float*)d_in[10];
    const float* msg_W = (const float*)d_in[11];
    const float* msg_b = (const float*)d_in[12];
    const float* ln2_g = (const float*)d_in[13];
    const float* ln2_b = (const float*)d_in[14];
    const float* cat_W = (const float*)d_in[15];
    const float* cat_b = (const float*)d_in[16];
    const float* inp_W = (const float*)d_in[17];
    const float* inp_b = (const float*)d_in[18];
    const float* bn_g  = (const float*)d_in[19];
    const float* bn_b  = (const float*)d_in[20];

    char* ws = (char*)d_ws;
    short* nodeW_t = (short*)(ws + 0);          // 294912
    short* imgW    = (short*)(ws + 294912);     // 1179648 (4 heads x 294912)
    short* Kv_all  = (short*)(ws + 1474560);    // 51,200,000
    short* Vv_all  = (short*)(ws + 52674560);   // 51,200,000
    float* resid   = (float*)(ws + 103874560);  // 25,600,000
    float* out1    = (float*)(ws + 129474560);  // 25,600,000
    float* stats   = (float*)(ws + 155074560);  // 1024

    hipFuncSetAttribute((const void*)edge_kernel,
                        hipFuncAttributeMaxDynamicSharedMemorySize, 100352);

    hipMemsetAsync(out1, 0, 25600000 + 1024, stream);   // out1 + stats (contiguous)
    prep_weights<<<2880, 256, 0, stream>>>(Kv2v, Vv2v, inp_W, Ke2v, Ve2v, lu_W, msg_W, cat_W,
                                           nodeW_t, imgW);
    node_proj<<<782, 256, 0, stream>>>(x, nodeW_t, Kv_all, Vv_all, resid);
    edge_kernel<<<3125, 256, 100352, stream>>>(ef, eidx, Kv_all, Vv_all, imgW,
                                               lu_b, ln1_g, ln1_b, msg_b,
                                               ln2_g, ln2_b, out1);
    bn_stats<<<391, 128, 0, stream>>>(out1, cat_b, stats);
    finalize<<<25000, 256, 0, stream>>>(out1, resid, stats, cat_b, bn_g, bn_b, inp_b,
                                        (float*)d_out);
}